// Round 2
// 749.591 us; speedup vs baseline: 1.0024x; 1.0024x over previous
//
#include <hip/hip_runtime.h>
#include <hip/hip_bf16.h>

#define TT 2048
#define BB 8
#define HH 8
#define NNS 32
#define MM (BB * TT)

typedef __attribute__((ext_vector_type(8))) short short8;
typedef __attribute__((ext_vector_type(4))) float f32x4;

__device__ __forceinline__ float bf2f(ushort u) {
    return __uint_as_float(((unsigned)u) << 16);
}
__device__ __forceinline__ ushort f2bf(float f) {
    unsigned x = __float_as_uint(f);
    unsigned r = (x + 0x7fffu + ((x >> 16) & 1u)) >> 16;
    return (ushort)r;
}
__device__ __forceinline__ float sigmoidf_fast(float x) {
    float e = __builtin_amdgcn_exp2f(x * -1.4426950408889634f);
    return __builtin_amdgcn_rcpf(1.0f + e);
}
__device__ __forceinline__ float tanhf_fast(float x) {
    // 1 - 2/(e^{2x}+1); exp2 over/underflow saturates to +-1, no clamp needed
    float e = __builtin_amdgcn_exp2f(x * 2.8853900817779268f);
    return fmaf(-2.0f, __builtin_amdgcn_rcpf(e + 1.0f), 1.0f);
}

template<int CTRL>
__device__ __forceinline__ float dpp_add(float x) {
    int y = __builtin_amdgcn_update_dpp(0, __float_as_int(x), CTRL, 0xF, 0xF, true);
    return x + __int_as_float(y);
}
// 16-lane rotate-reduce: every lane of each 16-lane row ends with the row sum.
__device__ __forceinline__ float red16(float x) {
    x = dpp_add<0xB1>(x);    // quad_perm xor1
    x = dpp_add<0x4E>(x);    // quad_perm xor2
    x = dpp_add<0x124>(x);   // row_ror:4
    x = dpp_add<0x128>(x);   // row_ror:8
    return x;
}

// Split 8 fp32 -> bf16 hi + bf16 lo planes, stored as 16B each.
__device__ __forceinline__ void stage8_split(const float* __restrict__ src,
                                             ushort* __restrict__ hi,
                                             ushort* __restrict__ lo) {
    float4 x0 = *reinterpret_cast<const float4*>(src);
    float4 x1 = *reinterpret_cast<const float4*>(src + 4);
    float xs[8] = {x0.x, x0.y, x0.z, x0.w, x1.x, x1.y, x1.z, x1.w};
    ushort h[8], l[8];
#pragma unroll
    for (int i = 0; i < 8; ++i) {
        ushort hh = f2bf(xs[i]);
        h[i] = hh;
        l[i] = f2bf(xs[i] - bf2f(hh));
    }
    *reinterpret_cast<uint4*>(hi) = *reinterpret_cast<const uint4*>(h);
    *reinterpret_cast<uint4*>(lo) = *reinterpret_cast<const uint4*>(l);
}
__device__ __forceinline__ void stage8_hi(const float* __restrict__ src,
                                          ushort* __restrict__ hi) {
    float4 x0 = *reinterpret_cast<const float4*>(src);
    float4 x1 = *reinterpret_cast<const float4*>(src + 4);
    float xs[8] = {x0.x, x0.y, x0.z, x0.w, x1.x, x1.y, x1.z, x1.w};
    ushort h[8];
#pragma unroll
    for (int i = 0; i < 8; ++i) h[i] = f2bf(xs[i]);
    *reinterpret_cast<uint4*>(hi) = *reinterpret_cast<const uint4*>(h);
}

// C[M,N] = act(A[M,K] @ W[N,K]^T), fp32 in/out, split-bf16 MFMA (hi+lo, 3 MFMAs).
template<int ACT>
__global__ __launch_bounds__(256) void gemm_split(
    const float* __restrict__ A,
    const float* __restrict__ W0, const float* __restrict__ W1,
    const float* __restrict__ W2, const float* __restrict__ W3,
    const float* __restrict__ bbeta,
    float* __restrict__ C, int M, int N, int K)
{
    __shared__ __align__(16) ushort Ah[64][40], Al[64][40];
    __shared__ __align__(16) ushort Wh[64][40], Wl[64][40];
    const int n0 = blockIdx.x * 64;
    const int m0 = blockIdx.y * 64;
    const int t  = threadIdx.x;
    const int wave = t >> 6, lane = t & 63;
    const int lr = lane & 15, lq = lane >> 4;

    const float* Wsel;
    {
        int wi = n0 >> 8;
        Wsel = (wi == 0) ? W0 : (wi == 1) ? W1 : (wi == 2) ? W2 : W3;
    }
    const int wr0 = n0 & 255;
    const int ar = t >> 2;
    const int ak = (t & 3) * 8;

    f32x4 acc[4];
#pragma unroll
    for (int c = 0; c < 4; ++c) acc[c] = (f32x4){0.f, 0.f, 0.f, 0.f};

    for (int k0 = 0; k0 < K; k0 += 32) {
        __syncthreads();
        stage8_split(&A[(size_t)(m0 + ar) * K + k0 + ak], &Ah[ar][ak], &Al[ar][ak]);
        stage8_split(&Wsel[(size_t)(wr0 + ar) * K + k0 + ak], &Wh[ar][ak], &Wl[ar][ak]);
        __syncthreads();
        short8 ah = *reinterpret_cast<const short8*>(&Ah[wave * 16 + lr][lq * 8]);
        short8 al = *reinterpret_cast<const short8*>(&Al[wave * 16 + lr][lq * 8]);
#pragma unroll
        for (int c = 0; c < 4; ++c) {
            short8 bh = *reinterpret_cast<const short8*>(&Wh[c * 16 + lr][lq * 8]);
            short8 bl = *reinterpret_cast<const short8*>(&Wl[c * 16 + lr][lq * 8]);
            acc[c] = __builtin_amdgcn_mfma_f32_16x16x32_bf16(ah, bh, acc[c], 0, 0, 0);
            acc[c] = __builtin_amdgcn_mfma_f32_16x16x32_bf16(ah, bl, acc[c], 0, 0, 0);
            acc[c] = __builtin_amdgcn_mfma_f32_16x16x32_bf16(al, bh, acc[c], 0, 0, 0);
        }
    }

#pragma unroll
    for (int c = 0; c < 4; ++c) {
#pragma unroll
        for (int r2 = 0; r2 < 4; ++r2) {
            int mg = m0 + wave * 16 + lq * 4 + r2;
            int ng = n0 + c * 16 + lr;
            float v = acc[c][r2];
            if (ACT == 1) v = v * sigmoidf_fast(v);
            if (ACT == 2 && ng >= 768) v = sigmoidf_fast(v + bbeta[ng - 768]);
            C[(size_t)mg * N + ng] = v;
        }
    }
}

// GEMM3: A is bf16 (cell), W fp32 -> bf16 hi only, C fp32.
__global__ __launch_bounds__(256) void gemm_bf_a(
    const ushort* __restrict__ A,
    const float* __restrict__ W0, const float* __restrict__ W1,
    const float* __restrict__ W2, const float* __restrict__ W3,
    float* __restrict__ C, int M, int N, int K)
{
    __shared__ __align__(16) ushort As[64][40];
    __shared__ __align__(16) ushort Ws[64][40];
    const int n0 = blockIdx.x * 64;
    const int m0 = blockIdx.y * 64;
    const int t  = threadIdx.x;
    const int wave = t >> 6, lane = t & 63;
    const int lr = lane & 15, lq = lane >> 4;

    const float* Wsel;
    {
        int wi = n0 >> 8;
        Wsel = (wi == 0) ? W0 : (wi == 1) ? W1 : (wi == 2) ? W2 : W3;
    }
    const int wr0 = n0 & 255;
    const int ar = t >> 2;
    const int ak = (t & 3) * 8;

    f32x4 acc[4];
#pragma unroll
    for (int c = 0; c < 4; ++c) acc[c] = (f32x4){0.f, 0.f, 0.f, 0.f};

    for (int k0 = 0; k0 < K; k0 += 32) {
        __syncthreads();
        *reinterpret_cast<uint4*>(&As[ar][ak]) =
            *reinterpret_cast<const uint4*>(&A[(size_t)(m0 + ar) * K + k0 + ak]);
        stage8_hi(&Wsel[(size_t)(wr0 + ar) * K + k0 + ak], &Ws[ar][ak]);
        __syncthreads();
        short8 af = *reinterpret_cast<const short8*>(&As[wave * 16 + lr][lq * 8]);
#pragma unroll
        for (int c = 0; c < 4; ++c) {
            short8 bfv = *reinterpret_cast<const short8*>(&Ws[c * 16 + lr][lq * 8]);
            acc[c] = __builtin_amdgcn_mfma_f32_16x16x32_bf16(af, bfv, acc[c], 0, 0, 0);
        }
    }

#pragma unroll
    for (int c = 0; c < 4; ++c) {
#pragma unroll
        for (int r2 = 0; r2 < 4; ++r2) {
            int mg = m0 + wave * 16 + lq * 4 + r2;
            int ng = n0 + c * 16 + lr;
            C[(size_t)mg * N + ng] = acc[c][r2];
        }
    }
}

// kn precompute: kn[b,t,h,j] = k / (||k||_h + 1e-6). Parallel over all (b,t,h).
__global__ __launch_bounds__(256) void kn_kernel(
    const float* __restrict__ P, float* __restrict__ KN)
{
    int idx = blockIdx.x * 256 + threadIdx.x;    // over MM*256
    int col = idx & 255;                          // h*32 + j
    int bt  = idx >> 8;
    float k = P[(size_t)bt * 1024 + col];
    float ks = k * k;
    ks += __shfl_xor(ks, 1, 32);  ks += __shfl_xor(ks, 2, 32);
    ks += __shfl_xor(ks, 4, 32);  ks += __shfl_xor(ks, 8, 32);
    ks += __shfl_xor(ks, 16, 32);
    KN[idx] = k * __builtin_amdgcn_rcpf(sqrtf(ks) + 1e-6f);
}

// Recurrent scan, fp32. 512 waves (2/CU), 4 rows/wave, 16 lanes/row (2 cols each).
// DPP rotate-reduce; 8-slot rotating register file at prefetch distance 7
// (6 streams x 8 slots = 48 VGPRs; launch_bounds(64,1) gives the allocator a
// 512-VGPR budget so the file stays live). Unroll 8 keeps every slot index
// compile-time. Tail of 8 steps is peeled so the hot loop has no clamp;
// row 2047 is loaded into the freed slot 7 before the tail. Stores batched
// 8 steps via lane-captured outputs. XCD-local batch mapping.
__global__ __launch_bounds__(64, 1) void scan_kernel(
    const float* __restrict__ P,
    const float* __restrict__ KN,
    ushort* __restrict__ cell,     // [B*T, 256] bf16
    float* __restrict__ Sout)      // [B,H,32,32] fp32
{
    const int b    = blockIdx.x & 7;     // XCD-local batch slice
    const int r    = blockIdx.x >> 3;    // 0..63
    const int h    = r & 7;
    const int quad = r >> 3;             // 0..7
    const int l    = threadIdx.x & 15;
    const int iw   = threadIdx.x >> 4;   // 0..3
    const int i    = quad * 4 + iw;

    const float* pb  = P  + (size_t)b * TT * 1024;
    const float* knb = KN + (size_t)b * TT * 256;
    const int okn0 = h * 32 + l,       okn1 = okn0 + 16;   // stride-256 rows
    const int oq0  = 512 + h * 32 + l, oq1  = oq0 + 16;    // stride-1024 rows
    const int ov   = 256 + h * 32 + i;
    const int ob   = 768 + h * 32 + i;

    // rotating prefetch file: row t lives in slot t&7, filled 7 iterations ahead
    float rkn0[8], rkn1[8], rq0[8], rq1[8], rv[8], rb[8];
#pragma unroll
    for (int d = 0; d < 7; ++d) {
        const float* prow = pb + (size_t)d * 1024;
        const float* krow = knb + (size_t)d * 256;
        rkn0[d] = krow[okn0]; rkn1[d] = krow[okn1];
        rq0[d]  = prow[oq0];  rq1[d]  = prow[oq1];
        rv[d]   = prow[ov];   rb[d]   = prow[ob];
    }

    float S0 = 0.f, S1 = 0.f, osv = 0.f;
    const size_t cb = (size_t)b * TT * 256 + h * 32 + i;

    // prefetch cursors: point at row t+7 at the top of step t
    const float* pf_p = pb + (size_t)7 * 1024;
    const float* pf_k = knb + (size_t)7 * 256;

#pragma unroll 8
    for (int t = 0; t < TT - 8; ++t) {
        // prefetch row t+7 into slot (t+7)&7 (last used at step t-1)
        {
            const int d7 = (t + 7) & 7;
            rkn0[d7] = pf_k[okn0]; rkn1[d7] = pf_k[okn1];
            rq0[d7]  = pf_p[oq0];  rq1[d7]  = pf_p[oq1];
            rv[d7]   = pf_p[ov];   rb[d7]   = pf_p[ob];
            pf_p += 1024; pf_k += 256;
        }

        const int dc = t & 7;
        // recurrence (critical chain: fma + 4 DPP + tanh)
        float p = red16(fmaf(S0, rkn0[dc], S1 * rkn1[dc]));
        float delta = rv[dc] - p;
        S0 = tanhf_fast(fmaf(rb[dc], S0, delta * rkn0[dc]));
        S1 = tanhf_fast(fmaf(rb[dc], S1, delta * rkn1[dc]));

        // output (off the recurrence chain); all lanes have sq after red16
        float sq = red16(fmaf(S0, rq0[dc], S1 * rq1[dc]));
        float o = sq * sq * sigmoidf_fast(sq);   // Sq * silu(Sq)
        osv = (l == dc) ? o : osv;               // lane t&7 captures step t

        if (dc == 7 && l < 8) {
            // lanes 0..7 of each 16-group store 8 consecutive steps at once
            cell[cb + (size_t)(t - 7 + l) * 256] = f2bf(osv);
        }
    }

    // slots now hold rows 2040..2046 in slots 0..6; slot 7 is free -> row 2047
    {
        const float* prow = pb + (size_t)(TT - 1) * 1024;
        const float* krow = knb + (size_t)(TT - 1) * 256;
        rkn0[7] = krow[okn0]; rkn1[7] = krow[okn1];
        rq0[7]  = prow[oq0];  rq1[7]  = prow[oq1];
        rv[7]   = prow[ov];   rb[7]   = prow[ob];
    }

#pragma unroll
    for (int t = TT - 8; t < TT; ++t) {
        const int dc = t & 7;
        float p = red16(fmaf(S0, rkn0[dc], S1 * rkn1[dc]));
        float delta = rv[dc] - p;
        S0 = tanhf_fast(fmaf(rb[dc], S0, delta * rkn0[dc]));
        S1 = tanhf_fast(fmaf(rb[dc], S1, delta * rkn1[dc]));

        float sq = red16(fmaf(S0, rq0[dc], S1 * rq1[dc]));
        float o = sq * sq * sigmoidf_fast(sq);
        osv = (l == dc) ? o : osv;

        if (dc == 7 && l < 8) {
            cell[cb + (size_t)(t - 7 + l) * 256] = f2bf(osv);
        }
    }

    float* so = Sout + (((size_t)(b * HH + h)) * NNS + i) * NNS;
    so[l] = S0;
    so[l + 16] = S1;
}

extern "C" void kernel_launch(void* const* d_in, const int* in_sizes, int n_in,
                              void* d_out, int out_size, void* d_ws, size_t ws_size,
                              hipStream_t stream) {
    const float* x     = (const float*)d_in[0];
    const float* W_in  = (const float*)d_in[1];
    const float* W_k   = (const float*)d_in[2];
    const float* W_v   = (const float*)d_in[3];
    const float* W_q   = (const float*)d_in[4];
    const float* W_b   = (const float*)d_in[5];
    const float* b_b   = (const float*)d_in[6];
    const float* W_out = (const float*)d_in[7];
    float* out = (float*)d_out;

    const int M = MM;                                    // 16384
    float*  xp   = (float*)d_ws;                         // M*1024 fp32
    float*  P    = xp + (size_t)M * 1024;                // M*1024 fp32
    float*  KN   = P  + (size_t)M * 1024;                // M*256  fp32
    ushort* cell = (ushort*)(KN + (size_t)M * 256);      // M*256  bf16

    dim3 blk(256);
    dim3 g1(1024 / 64, M / 64);

    // 1) xp = silu(x @ W_in^T)
    gemm_split<1><<<g1, blk, 0, stream>>>(x, W_in, W_in + 256 * 1024,
                                          W_in + 512 * 1024, W_in + 768 * 1024,
                                          b_b, xp, M, 1024, 1024);
    // 2) P = xp @ [Wk;Wv;Wq;Wbeta]^T, beta block: sigmoid(. + b_beta)
    gemm_split<2><<<g1, blk, 0, stream>>>(xp, W_k, W_v, W_q, W_b,
                                          b_b, P, M, 1024, 1024);
    // 3) kn = k / (||k|| + 1e-6)  (parallel, memory-bound)
    kn_kernel<<<dim3((M * 256) / 256), blk, 0, stream>>>(P, KN);
    // 4) recurrent scan -> cell (bf16) + S_final (fp32, d_out tail)
    scan_kernel<<<dim3(512), dim3(64), 0, stream>>>(P, KN, cell, out + (size_t)M * 1024);
    // 5) y = cell @ W_out^T
    gemm_bf_a<<<g1, blk, 0, stream>>>(cell, W_out, W_out + 256 * 256,
                                      W_out + 512 * 256, W_out + 768 * 256,
                                      out, M, 1024, 256);
}

// Round 3
// 684.717 us; speedup vs baseline: 1.0974x; 1.0947x over previous
//
#include <hip/hip_runtime.h>
#include <hip/hip_bf16.h>

#define TT 2048
#define BB 8
#define HH 8
#define NNS 32
#define MM (BB * TT)
#define CH 16   // scan chunk rows staged in LDS

typedef __attribute__((ext_vector_type(8))) short short8;
typedef __attribute__((ext_vector_type(4))) float f32x4;

__device__ __forceinline__ float bf2f(ushort u) {
    return __uint_as_float(((unsigned)u) << 16);
}
__device__ __forceinline__ ushort f2bf(float f) {
    unsigned x = __float_as_uint(f);
    unsigned r = (x + 0x7fffu + ((x >> 16) & 1u)) >> 16;
    return (ushort)r;
}
__device__ __forceinline__ float sigmoidf_fast(float x) {
    float e = __builtin_amdgcn_exp2f(x * -1.4426950408889634f);
    return __builtin_amdgcn_rcpf(1.0f + e);
}
__device__ __forceinline__ float tanhf_fast(float x) {
    // 1 - 2/(e^{2x}+1); exp2 over/underflow saturates to +-1, no clamp needed
    float e = __builtin_amdgcn_exp2f(x * 2.8853900817779268f);
    return fmaf(-2.0f, __builtin_amdgcn_rcpf(e + 1.0f), 1.0f);
}

template<int CTRL>
__device__ __forceinline__ float dpp_add(float x) {
    int y = __builtin_amdgcn_update_dpp(0, __float_as_int(x), CTRL, 0xF, 0xF, true);
    return x + __int_as_float(y);
}
// 16-lane rotate-reduce: every lane of each 16-lane row ends with the row sum.
__device__ __forceinline__ float red16(float x) {
    x = dpp_add<0xB1>(x);    // quad_perm xor1
    x = dpp_add<0x4E>(x);    // quad_perm xor2
    x = dpp_add<0x124>(x);   // row_ror:4
    x = dpp_add<0x128>(x);   // row_ror:8
    return x;
}

// Split 8 fp32 -> bf16 hi + bf16 lo planes, stored as 16B each.
__device__ __forceinline__ void stage8_split(const float* __restrict__ src,
                                             ushort* __restrict__ hi,
                                             ushort* __restrict__ lo) {
    float4 x0 = *reinterpret_cast<const float4*>(src);
    float4 x1 = *reinterpret_cast<const float4*>(src + 4);
    float xs[8] = {x0.x, x0.y, x0.z, x0.w, x1.x, x1.y, x1.z, x1.w};
    ushort h[8], l[8];
#pragma unroll
    for (int i = 0; i < 8; ++i) {
        ushort hh = f2bf(xs[i]);
        h[i] = hh;
        l[i] = f2bf(xs[i] - bf2f(hh));
    }
    *reinterpret_cast<uint4*>(hi) = *reinterpret_cast<const uint4*>(h);
    *reinterpret_cast<uint4*>(lo) = *reinterpret_cast<const uint4*>(l);
}
__device__ __forceinline__ void stage8_hi(const float* __restrict__ src,
                                          ushort* __restrict__ hi) {
    float4 x0 = *reinterpret_cast<const float4*>(src);
    float4 x1 = *reinterpret_cast<const float4*>(src + 4);
    float xs[8] = {x0.x, x0.y, x0.z, x0.w, x1.x, x1.y, x1.z, x1.w};
    ushort h[8];
#pragma unroll
    for (int i = 0; i < 8; ++i) h[i] = f2bf(xs[i]);
    *reinterpret_cast<uint4*>(hi) = *reinterpret_cast<const uint4*>(h);
}

// C[M,N] = act(A[M,K] @ W[N,K]^T), fp32 in/out, split-bf16 MFMA (hi+lo, 3 MFMAs).
template<int ACT>
__global__ __launch_bounds__(256) void gemm_split(
    const float* __restrict__ A,
    const float* __restrict__ W0, const float* __restrict__ W1,
    const float* __restrict__ W2, const float* __restrict__ W3,
    const float* __restrict__ bbeta,
    float* __restrict__ C, int M, int N, int K)
{
    __shared__ __align__(16) ushort Ah[64][40], Al[64][40];
    __shared__ __align__(16) ushort Wh[64][40], Wl[64][40];
    const int n0 = blockIdx.x * 64;
    const int m0 = blockIdx.y * 64;
    const int t  = threadIdx.x;
    const int wave = t >> 6, lane = t & 63;
    const int lr = lane & 15, lq = lane >> 4;

    const float* Wsel;
    {
        int wi = n0 >> 8;
        Wsel = (wi == 0) ? W0 : (wi == 1) ? W1 : (wi == 2) ? W2 : W3;
    }
    const int wr0 = n0 & 255;
    const int ar = t >> 2;
    const int ak = (t & 3) * 8;

    f32x4 acc[4];
#pragma unroll
    for (int c = 0; c < 4; ++c) acc[c] = (f32x4){0.f, 0.f, 0.f, 0.f};

    for (int k0 = 0; k0 < K; k0 += 32) {
        __syncthreads();
        stage8_split(&A[(size_t)(m0 + ar) * K + k0 + ak], &Ah[ar][ak], &Al[ar][ak]);
        stage8_split(&Wsel[(size_t)(wr0 + ar) * K + k0 + ak], &Wh[ar][ak], &Wl[ar][ak]);
        __syncthreads();
        short8 ah = *reinterpret_cast<const short8*>(&Ah[wave * 16 + lr][lq * 8]);
        short8 al = *reinterpret_cast<const short8*>(&Al[wave * 16 + lr][lq * 8]);
#pragma unroll
        for (int c = 0; c < 4; ++c) {
            short8 bh = *reinterpret_cast<const short8*>(&Wh[c * 16 + lr][lq * 8]);
            short8 bl = *reinterpret_cast<const short8*>(&Wl[c * 16 + lr][lq * 8]);
            acc[c] = __builtin_amdgcn_mfma_f32_16x16x32_bf16(ah, bh, acc[c], 0, 0, 0);
            acc[c] = __builtin_amdgcn_mfma_f32_16x16x32_bf16(ah, bl, acc[c], 0, 0, 0);
            acc[c] = __builtin_amdgcn_mfma_f32_16x16x32_bf16(al, bh, acc[c], 0, 0, 0);
        }
    }

#pragma unroll
    for (int c = 0; c < 4; ++c) {
#pragma unroll
        for (int r2 = 0; r2 < 4; ++r2) {
            int mg = m0 + wave * 16 + lq * 4 + r2;
            int ng = n0 + c * 16 + lr;
            float v = acc[c][r2];
            if (ACT == 1) v = v * sigmoidf_fast(v);
            if (ACT == 2 && ng >= 768) v = sigmoidf_fast(v + bbeta[ng - 768]);
            C[(size_t)mg * N + ng] = v;
        }
    }
}

// GEMM3: A is bf16 (cell), W fp32 -> bf16 hi only, C fp32.
__global__ __launch_bounds__(256) void gemm_bf_a(
    const ushort* __restrict__ A,
    const float* __restrict__ W0, const float* __restrict__ W1,
    const float* __restrict__ W2, const float* __restrict__ W3,
    float* __restrict__ C, int M, int N, int K)
{
    __shared__ __align__(16) ushort As[64][40];
    __shared__ __align__(16) ushort Ws[64][40];
    const int n0 = blockIdx.x * 64;
    const int m0 = blockIdx.y * 64;
    const int t  = threadIdx.x;
    const int wave = t >> 6, lane = t & 63;
    const int lr = lane & 15, lq = lane >> 4;

    const float* Wsel;
    {
        int wi = n0 >> 8;
        Wsel = (wi == 0) ? W0 : (wi == 1) ? W1 : (wi == 2) ? W2 : W3;
    }
    const int wr0 = n0 & 255;
    const int ar = t >> 2;
    const int ak = (t & 3) * 8;

    f32x4 acc[4];
#pragma unroll
    for (int c = 0; c < 4; ++c) acc[c] = (f32x4){0.f, 0.f, 0.f, 0.f};

    for (int k0 = 0; k0 < K; k0 += 32) {
        __syncthreads();
        *reinterpret_cast<uint4*>(&As[ar][ak]) =
            *reinterpret_cast<const uint4*>(&A[(size_t)(m0 + ar) * K + k0 + ak]);
        stage8_hi(&Wsel[(size_t)(wr0 + ar) * K + k0 + ak], &Ws[ar][ak]);
        __syncthreads();
        short8 af = *reinterpret_cast<const short8*>(&As[wave * 16 + lr][lq * 8]);
#pragma unroll
        for (int c = 0; c < 4; ++c) {
            short8 bfv = *reinterpret_cast<const short8*>(&Ws[c * 16 + lr][lq * 8]);
            acc[c] = __builtin_amdgcn_mfma_f32_16x16x32_bf16(af, bfv, acc[c], 0, 0, 0);
        }
    }

#pragma unroll
    for (int c = 0; c < 4; ++c) {
#pragma unroll
        for (int r2 = 0; r2 < 4; ++r2) {
            int mg = m0 + wave * 16 + lq * 4 + r2;
            int ng = n0 + c * 16 + lr;
            C[(size_t)mg * N + ng] = acc[c][r2];
        }
    }
}

// kn precompute: kn[b,t,h,j] = k / (||k||_h + 1e-6). Parallel over all (b,t,h).
__global__ __launch_bounds__(256) void kn_kernel(
    const float* __restrict__ P, float* __restrict__ KN)
{
    int idx = blockIdx.x * 256 + threadIdx.x;    // over MM*256
    int col = idx & 255;                          // h*32 + j
    int bt  = idx >> 8;
    float k = P[(size_t)bt * 1024 + col];
    float ks = k * k;
    ks += __shfl_xor(ks, 1, 32);  ks += __shfl_xor(ks, 2, 32);
    ks += __shfl_xor(ks, 4, 32);  ks += __shfl_xor(ks, 8, 32);
    ks += __shfl_xor(ks, 16, 32);
    KN[idx] = k * __builtin_amdgcn_rcpf(sqrtf(ks) + 1e-6f);
}

// ---------------- scan: LDS chunk-staged (T14 async split) ----------------
// One 64-thread wave per block; 512 blocks (b,h,quad). Per chunk of 16 rows:
// issue 6 coalesced global loads EARLY, compute 16 steps from current LDS buf
// (per-step ds_reads prefetched distance-2 into a 4-slot register pipeline,
// all indices compile-time), ds_write the staged regs into the OTHER buf LATE
// (vmcnt covered by the 16-step compute), then preload the next buf's first
// two steps. Separate named __shared__ arrays per buffer so AA never inserts
// a spurious wait between staging and current-buffer reads. No barriers.
template<int DO_STAGE>
__device__ __forceinline__ void scan_chunk(
    float (&K_)[CH][32], float (&Q_)[CH][32], float (&V_)[CH][4], float (&B_)[CH][4],
    float (&NK)[CH][32], float (&NQ)[CH][32], float (&NV)[CH][4], float (&NB)[CH][4],
    const float*& gkn, const float*& gq, const float*& gv, const float*& gb,
    float (&rk0)[4], float (&rk1)[4], float (&rq0)[4], float (&rq1)[4],
    float (&rv)[4], float (&rb)[4],
    float& S0, float& S1, float& osv,
    ushort* __restrict__ cell, size_t crow,
    int l, int iw, int j)
{
    float4 Lk0, Lk1, Lq0, Lq1;
    float Lv = 0.f, Lb = 0.f;
    if (DO_STAGE) {
        // issue-early: HBM/L2 latency hides under the 16 steps below
        Lk0 = *reinterpret_cast<const float4*>(gkn);
        Lk1 = *reinterpret_cast<const float4*>(gkn + 8 * 256);
        Lq0 = *reinterpret_cast<const float4*>(gq);
        Lq1 = *reinterpret_cast<const float4*>(gq + 8 * 1024);
        Lv  = *gv;
        Lb  = *gb;
        gkn += CH * 256; gq += CH * 1024; gv += CH * 1024; gb += CH * 1024;
    }
#pragma unroll
    for (int tl = 0; tl < CH; ++tl) {
        if (tl < CH - 2) {
            // distance-2 LDS prefetch into slot (tl+2)&3
            const int dn = (tl + 2) & 3;
            rk0[dn] = K_[tl + 2][l];   rk1[dn] = K_[tl + 2][l + 16];
            rq0[dn] = Q_[tl + 2][l];   rq1[dn] = Q_[tl + 2][l + 16];
            rv[dn]  = V_[tl + 2][iw];  rb[dn]  = B_[tl + 2][iw];
        }
        const int sl = tl & 3;
        // recurrence critical chain: fma + 4 DPP + tanh
        float p = red16(fmaf(S0, rk0[sl], S1 * rk1[sl]));
        float delta = rv[sl] - p;
        S0 = tanhf_fast(fmaf(rb[sl], S0, delta * rk0[sl]));
        S1 = tanhf_fast(fmaf(rb[sl], S1, delta * rk1[sl]));
        // output: capture sq; silu deferred to the batched store
        float sq = red16(fmaf(S0, rq0[sl], S1 * rq1[sl]));
        osv = (l == (tl & 7)) ? sq : osv;
        if ((tl & 7) == 7 && l < 8) {
            float o = osv * osv * sigmoidf_fast(osv);   // Sq * silu(Sq)
            cell[crow + (size_t)(tl - 7 + l) * 256] = f2bf(o);
        }
    }
    if (DO_STAGE) {
        // write-late: global loads have had 16 steps to land
        *reinterpret_cast<float4*>(&NK[j >> 3][(j & 7) * 4]) = Lk0;
        *reinterpret_cast<float4*>(&NK[8 + (j >> 3)][(j & 7) * 4]) = Lk1;
        *reinterpret_cast<float4*>(&NQ[j >> 3][(j & 7) * 4]) = Lq0;
        *reinterpret_cast<float4*>(&NQ[8 + (j >> 3)][(j & 7) * 4]) = Lq1;
        NV[j >> 2][j & 3] = Lv;
        NB[j >> 2][j & 3] = Lb;
        // preload next chunk's steps 0,1 into the pipeline
#pragma unroll
        for (int d = 0; d < 2; ++d) {
            rk0[d] = NK[d][l];  rk1[d] = NK[d][l + 16];
            rq0[d] = NQ[d][l];  rq1[d] = NQ[d][l + 16];
            rv[d]  = NV[d][iw]; rb[d]  = NB[d][iw];
        }
    }
}

__global__ __launch_bounds__(64, 1) void scan_kernel(
    const float* __restrict__ P,
    const float* __restrict__ KN,
    ushort* __restrict__ cell,     // [B*T, 256] bf16
    float* __restrict__ Sout)      // [B,H,32,32] fp32
{
    const int b    = blockIdx.x & 7;     // XCD-local batch slice
    const int r    = blockIdx.x >> 3;    // 0..63
    const int h    = r & 7;
    const int quad = r >> 3;             // 0..7
    const int j    = threadIdx.x;
    const int l    = j & 15;
    const int iw   = j >> 4;             // 0..3
    const int i    = quad * 4 + iw;

    __shared__ __align__(16) float sKN0[CH][32], sKN1[CH][32];
    __shared__ __align__(16) float sQ0[CH][32],  sQ1[CH][32];
    __shared__ __align__(16) float sV0[CH][4],   sV1[CH][4];
    __shared__ __align__(16) float sB0[CH][4],   sB1[CH][4];

    const size_t bt0 = (size_t)b * TT;
    // per-lane coalesced source cursors (point at next chunk to stage)
    const float* gkn = KN + (bt0 + (j >> 3)) * 256 + h * 32 + (j & 7) * 4;
    const float* gq  = P  + (bt0 + (j >> 3)) * 1024 + 512 + h * 32 + (j & 7) * 4;
    const float* gv  = P  + (bt0 + (j >> 2)) * 1024 + 256 + h * 32 + quad * 4 + (j & 3);
    const float* gb  = P  + (bt0 + (j >> 2)) * 1024 + 768 + h * 32 + quad * 4 + (j & 3);

    float rk0[4], rk1[4], rq0[4], rq1[4], rv[4], rb[4];
    float S0 = 0.f, S1 = 0.f, osv = 0.f;
    const size_t cb = (size_t)b * TT * 256 + h * 32 + i;

    // prologue: stage chunk 0 into buf0, preload steps 0,1
    {
        float4 k0 = *reinterpret_cast<const float4*>(gkn);
        float4 k1 = *reinterpret_cast<const float4*>(gkn + 8 * 256);
        float4 q0 = *reinterpret_cast<const float4*>(gq);
        float4 q1 = *reinterpret_cast<const float4*>(gq + 8 * 1024);
        float v0 = *gv, b0 = *gb;
        gkn += CH * 256; gq += CH * 1024; gv += CH * 1024; gb += CH * 1024;
        *reinterpret_cast<float4*>(&sKN0[j >> 3][(j & 7) * 4]) = k0;
        *reinterpret_cast<float4*>(&sKN0[8 + (j >> 3)][(j & 7) * 4]) = k1;
        *reinterpret_cast<float4*>(&sQ0[j >> 3][(j & 7) * 4]) = q0;
        *reinterpret_cast<float4*>(&sQ0[8 + (j >> 3)][(j & 7) * 4]) = q1;
        sV0[j >> 2][j & 3] = v0;
        sB0[j >> 2][j & 3] = b0;
#pragma unroll
        for (int d = 0; d < 2; ++d) {
            rk0[d] = sKN0[d][l];  rk1[d] = sKN0[d][l + 16];
            rq0[d] = sQ0[d][l];   rq1[d] = sQ0[d][l + 16];
            rv[d]  = sV0[d][iw];  rb[d]  = sB0[d][iw];
        }
    }

    size_t crow = cb;
    for (int c = 0; c < 126; c += 2) {
        scan_chunk<1>(sKN0, sQ0, sV0, sB0, sKN1, sQ1, sV1, sB1,
                      gkn, gq, gv, gb, rk0, rk1, rq0, rq1, rv, rb,
                      S0, S1, osv, cell, crow, l, iw, j);
        crow += (size_t)CH * 256;
        scan_chunk<1>(sKN1, sQ1, sV1, sB1, sKN0, sQ0, sV0, sB0,
                      gkn, gq, gv, gb, rk0, rk1, rq0, rq1, rv, rb,
                      S0, S1, osv, cell, crow, l, iw, j);
        crow += (size_t)CH * 256;
    }
    // chunk 126 (buf0), stages chunk 127 -> buf1
    scan_chunk<1>(sKN0, sQ0, sV0, sB0, sKN1, sQ1, sV1, sB1,
                  gkn, gq, gv, gb, rk0, rk1, rq0, rq1, rv, rb,
                  S0, S1, osv, cell, crow, l, iw, j);
    crow += (size_t)CH * 256;
    // chunk 127 (buf1), no staging
    scan_chunk<0>(sKN1, sQ1, sV1, sB1, sKN0, sQ0, sV0, sB0,
                  gkn, gq, gv, gb, rk0, rk1, rq0, rq1, rv, rb,
                  S0, S1, osv, cell, crow, l, iw, j);

    float* so = Sout + (((size_t)(b * HH + h)) * NNS + i) * NNS;
    so[l] = S0;
    so[l + 16] = S1;
}

extern "C" void kernel_launch(void* const* d_in, const int* in_sizes, int n_in,
                              void* d_out, int out_size, void* d_ws, size_t ws_size,
                              hipStream_t stream) {
    const float* x     = (const float*)d_in[0];
    const float* W_in  = (const float*)d_in[1];
    const float* W_k   = (const float*)d_in[2];
    const float* W_v   = (const float*)d_in[3];
    const float* W_q   = (const float*)d_in[4];
    const float* W_b   = (const float*)d_in[5];
    const float* b_b   = (const float*)d_in[6];
    const float* W_out = (const float*)d_in[7];
    float* out = (float*)d_out;

    const int M = MM;                                    // 16384
    float*  xp   = (float*)d_ws;                         // M*1024 fp32
    float*  P    = xp + (size_t)M * 1024;                // M*1024 fp32
    float*  KN   = P  + (size_t)M * 1024;                // M*256  fp32
    ushort* cell = (ushort*)(KN + (size_t)M * 256);      // M*256  bf16

    dim3 blk(256);
    dim3 g1(1024 / 64, M / 64);

    // 1) xp = silu(x @ W_in^T)
    gemm_split<1><<<g1, blk, 0, stream>>>(x, W_in, W_in + 256 * 1024,
                                          W_in + 512 * 1024, W_in + 768 * 1024,
                                          b_b, xp, M, 1024, 1024);
    // 2) P = xp @ [Wk;Wv;Wq;Wbeta]^T, beta block: sigmoid(. + b_beta)
    gemm_split<2><<<g1, blk, 0, stream>>>(xp, W_k, W_v, W_q, W_b,
                                          b_b, P, M, 1024, 1024);
    // 3) kn = k / (||k|| + 1e-6)  (parallel, memory-bound)
    kn_kernel<<<dim3((M * 256) / 256), blk, 0, stream>>>(P, KN);
    // 4) recurrent scan -> cell (bf16) + S_final (fp32, d_out tail)
    scan_kernel<<<dim3(512), dim3(64), 0, stream>>>(P, KN, cell, out + (size_t)M * 1024);
    // 5) y = cell @ W_out^T
    gemm_bf_a<<<g1, blk, 0, stream>>>(cell, W_out, W_out + 256 * 256,
                                      W_out + 512 * 256, W_out + 768 * 256,
                                      out, M, 1024, 256);
}

// Round 4
// 677.867 us; speedup vs baseline: 1.1085x; 1.0101x over previous
//
#include <hip/hip_runtime.h>
#include <hip/hip_bf16.h>

#define TT 2048
#define BB 8
#define HH 8
#define NNS 32
#define MM (BB * TT)
#define CH 16   // scan chunk rows staged in LDS

typedef __attribute__((ext_vector_type(8))) short short8;
typedef __attribute__((ext_vector_type(4))) float f32x4;

__device__ __forceinline__ float bf2f(ushort u) {
    return __uint_as_float(((unsigned)u) << 16);
}
__device__ __forceinline__ ushort f2bf(float f) {
    unsigned x = __float_as_uint(f);
    unsigned r = (x + 0x7fffu + ((x >> 16) & 1u)) >> 16;
    return (ushort)r;
}
__device__ __forceinline__ float sigmoidf_fast(float x) {
    float e = __builtin_amdgcn_exp2f(x * -1.4426950408889634f);
    return __builtin_amdgcn_rcpf(1.0f + e);
}
__device__ __forceinline__ float tanhf_fast(float x) {
    // 1 - 2/(e^{2x}+1); exp2 over/underflow saturates to +-1, no clamp needed
    float e = __builtin_amdgcn_exp2f(x * 2.8853900817779268f);
    return fmaf(-2.0f, __builtin_amdgcn_rcpf(e + 1.0f), 1.0f);
}

template<int CTRL>
__device__ __forceinline__ float dpp_add(float x) {
    int y = __builtin_amdgcn_update_dpp(0, __float_as_int(x), CTRL, 0xF, 0xF, true);
    return x + __int_as_float(y);
}
// 16-lane rotate-reduce: every lane of each 16-lane row ends with the row sum.
__device__ __forceinline__ float red16(float x) {
    x = dpp_add<0xB1>(x);    // quad_perm xor1
    x = dpp_add<0x4E>(x);    // quad_perm xor2
    x = dpp_add<0x124>(x);   // row_ror:4
    x = dpp_add<0x128>(x);   // row_ror:8
    return x;
}

// Split 8 fp32 -> bf16 hi + bf16 lo planes, stored as 16B each.
__device__ __forceinline__ void stage8_split(const float* __restrict__ src,
                                             ushort* __restrict__ hi,
                                             ushort* __restrict__ lo) {
    float4 x0 = *reinterpret_cast<const float4*>(src);
    float4 x1 = *reinterpret_cast<const float4*>(src + 4);
    float xs[8] = {x0.x, x0.y, x0.z, x0.w, x1.x, x1.y, x1.z, x1.w};
    ushort h[8], l[8];
#pragma unroll
    for (int i = 0; i < 8; ++i) {
        ushort hh = f2bf(xs[i]);
        h[i] = hh;
        l[i] = f2bf(xs[i] - bf2f(hh));
    }
    *reinterpret_cast<uint4*>(hi) = *reinterpret_cast<const uint4*>(h);
    *reinterpret_cast<uint4*>(lo) = *reinterpret_cast<const uint4*>(l);
}
__device__ __forceinline__ void stage8_hi(const float* __restrict__ src,
                                          ushort* __restrict__ hi) {
    float4 x0 = *reinterpret_cast<const float4*>(src);
    float4 x1 = *reinterpret_cast<const float4*>(src + 4);
    float xs[8] = {x0.x, x0.y, x0.z, x0.w, x1.x, x1.y, x1.z, x1.w};
    ushort h[8];
#pragma unroll
    for (int i = 0; i < 8; ++i) h[i] = f2bf(xs[i]);
    *reinterpret_cast<uint4*>(hi) = *reinterpret_cast<const uint4*>(h);
}

// C[M,N] = act(A[M,K] @ W[N,K]^T), fp32 in/out, split-bf16 MFMA (hi+lo, 3 MFMAs).
template<int ACT>
__global__ __launch_bounds__(256) void gemm_split(
    const float* __restrict__ A,
    const float* __restrict__ W0, const float* __restrict__ W1,
    const float* __restrict__ W2, const float* __restrict__ W3,
    const float* __restrict__ bbeta,
    float* __restrict__ C, int M, int N, int K)
{
    __shared__ __align__(16) ushort Ah[64][40], Al[64][40];
    __shared__ __align__(16) ushort Wh[64][40], Wl[64][40];
    const int n0 = blockIdx.x * 64;
    const int m0 = blockIdx.y * 64;
    const int t  = threadIdx.x;
    const int wave = t >> 6, lane = t & 63;
    const int lr = lane & 15, lq = lane >> 4;

    const float* Wsel;
    {
        int wi = n0 >> 8;
        Wsel = (wi == 0) ? W0 : (wi == 1) ? W1 : (wi == 2) ? W2 : W3;
    }
    const int wr0 = n0 & 255;
    const int ar = t >> 2;
    const int ak = (t & 3) * 8;

    f32x4 acc[4];
#pragma unroll
    for (int c = 0; c < 4; ++c) acc[c] = (f32x4){0.f, 0.f, 0.f, 0.f};

    for (int k0 = 0; k0 < K; k0 += 32) {
        __syncthreads();
        stage8_split(&A[(size_t)(m0 + ar) * K + k0 + ak], &Ah[ar][ak], &Al[ar][ak]);
        stage8_split(&Wsel[(size_t)(wr0 + ar) * K + k0 + ak], &Wh[ar][ak], &Wl[ar][ak]);
        __syncthreads();
        short8 ah = *reinterpret_cast<const short8*>(&Ah[wave * 16 + lr][lq * 8]);
        short8 al = *reinterpret_cast<const short8*>(&Al[wave * 16 + lr][lq * 8]);
#pragma unroll
        for (int c = 0; c < 4; ++c) {
            short8 bh = *reinterpret_cast<const short8*>(&Wh[c * 16 + lr][lq * 8]);
            short8 bl = *reinterpret_cast<const short8*>(&Wl[c * 16 + lr][lq * 8]);
            acc[c] = __builtin_amdgcn_mfma_f32_16x16x32_bf16(ah, bh, acc[c], 0, 0, 0);
            acc[c] = __builtin_amdgcn_mfma_f32_16x16x32_bf16(ah, bl, acc[c], 0, 0, 0);
            acc[c] = __builtin_amdgcn_mfma_f32_16x16x32_bf16(al, bh, acc[c], 0, 0, 0);
        }
    }

#pragma unroll
    for (int c = 0; c < 4; ++c) {
#pragma unroll
        for (int r2 = 0; r2 < 4; ++r2) {
            int mg = m0 + wave * 16 + lq * 4 + r2;
            int ng = n0 + c * 16 + lr;
            float v = acc[c][r2];
            if (ACT == 1) v = v * sigmoidf_fast(v);
            if (ACT == 2 && ng >= 768) v = sigmoidf_fast(v + bbeta[ng - 768]);
            C[(size_t)mg * N + ng] = v;
        }
    }
}

// GEMM3: A is bf16 (cell), W fp32 -> bf16 hi only, C fp32.
__global__ __launch_bounds__(256) void gemm_bf_a(
    const ushort* __restrict__ A,
    const float* __restrict__ W0, const float* __restrict__ W1,
    const float* __restrict__ W2, const float* __restrict__ W3,
    float* __restrict__ C, int M, int N, int K)
{
    __shared__ __align__(16) ushort As[64][40];
    __shared__ __align__(16) ushort Ws[64][40];
    const int n0 = blockIdx.x * 64;
    const int m0 = blockIdx.y * 64;
    const int t  = threadIdx.x;
    const int wave = t >> 6, lane = t & 63;
    const int lr = lane & 15, lq = lane >> 4;

    const float* Wsel;
    {
        int wi = n0 >> 8;
        Wsel = (wi == 0) ? W0 : (wi == 1) ? W1 : (wi == 2) ? W2 : W3;
    }
    const int wr0 = n0 & 255;
    const int ar = t >> 2;
    const int ak = (t & 3) * 8;

    f32x4 acc[4];
#pragma unroll
    for (int c = 0; c < 4; ++c) acc[c] = (f32x4){0.f, 0.f, 0.f, 0.f};

    for (int k0 = 0; k0 < K; k0 += 32) {
        __syncthreads();
        *reinterpret_cast<uint4*>(&As[ar][ak]) =
            *reinterpret_cast<const uint4*>(&A[(size_t)(m0 + ar) * K + k0 + ak]);
        stage8_hi(&Wsel[(size_t)(wr0 + ar) * K + k0 + ak], &Ws[ar][ak]);
        __syncthreads();
        short8 af = *reinterpret_cast<const short8*>(&As[wave * 16 + lr][lq * 8]);
#pragma unroll
        for (int c = 0; c < 4; ++c) {
            short8 bfv = *reinterpret_cast<const short8*>(&Ws[c * 16 + lr][lq * 8]);
            acc[c] = __builtin_amdgcn_mfma_f32_16x16x32_bf16(af, bfv, acc[c], 0, 0, 0);
        }
    }

#pragma unroll
    for (int c = 0; c < 4; ++c) {
#pragma unroll
        for (int r2 = 0; r2 < 4; ++r2) {
            int mg = m0 + wave * 16 + lq * 4 + r2;
            int ng = n0 + c * 16 + lr;
            C[(size_t)mg * N + ng] = acc[c][r2];
        }
    }
}

// kn precompute: kn[b,t,h,j] = k / (||k||_h + 1e-6). Parallel over all (b,t,h).
__global__ __launch_bounds__(256) void kn_kernel(
    const float* __restrict__ P, float* __restrict__ KN)
{
    int idx = blockIdx.x * 256 + threadIdx.x;    // over MM*256
    int col = idx & 255;                          // h*32 + j
    int bt  = idx >> 8;
    float k = P[(size_t)bt * 1024 + col];
    float ks = k * k;
    ks += __shfl_xor(ks, 1, 32);  ks += __shfl_xor(ks, 2, 32);
    ks += __shfl_xor(ks, 4, 32);  ks += __shfl_xor(ks, 8, 32);
    ks += __shfl_xor(ks, 16, 32);
    KN[idx] = k * __builtin_amdgcn_rcpf(sqrtf(ks) + 1e-6f);
}

// ---------------- scan: LDS chunk-staged + 8-step register batching ----------
// One 64-thread wave per block; 512 blocks (b,h,quad). Two LDS chunk buffers
// (16 rows each) + two 8-step register buffers. Per chunk: issue 6 coalesced
// global loads EARLY; batch-read rows 8-15 into regB; compute steps 0-7 from
// regA (pure VALU, no memory on the serial path); flush outputs; write staged
// globals into the other LDS buf; batch-read its rows 0-7 into regA; compute
// steps 8-15 from regB; flush. The sq-reduce is deferred: per step only a
// 2-op partial is captured; every 8 steps the 8 INDEPENDENT red16s pipeline
// (issue-bound), then a 7-cndmask lane-select tree + silu + store.
__device__ __forceinline__ void lds_load8(
    float (&K_)[CH][32], float (&Q_)[CH][32], float (&VB)[CH][8],
    int base, int l, int iw,
    float (&k0)[8], float (&k1)[8], float (&q0)[8], float (&q1)[8],
    float (&vv)[8], float (&bb)[8])
{
#pragma unroll
    for (int u = 0; u < 8; ++u) {
        k0[u] = K_[base + u][l];  k1[u] = K_[base + u][l + 16];
        q0[u] = Q_[base + u][l];  q1[u] = Q_[base + u][l + 16];
        vv[u] = VB[base + u][iw]; bb[u] = VB[base + u][iw + 4];
    }
}

__device__ __forceinline__ void steps8(
    float (&k0)[8], float (&k1)[8], float (&q0)[8], float (&q1)[8],
    float (&vv)[8], float (&bb)[8],
    float& S0, float& S1, float (&sqp)[8])
{
#pragma unroll
    for (int u = 0; u < 8; ++u) {
        // recurrence critical chain: fma + 4 DPP + sub + fma + tanh
        float p = red16(fmaf(S0, k0[u], S1 * k1[u]));
        float delta = vv[u] - p;
        S0 = tanhf_fast(fmaf(bb[u], S0, delta * k0[u]));
        S1 = tanhf_fast(fmaf(bb[u], S1, delta * k1[u]));
        // off-chain: 2-op partial only; reduce deferred to flush8
        sqp[u] = fmaf(S0, q0[u], S1 * q1[u]);
    }
}

__device__ __forceinline__ void flush8(
    float (&sqp)[8], ushort* __restrict__ cell, size_t crow, int l)
{
    // 8 independent reduces: pipeline, issue-bound not latency-bound
    float r0 = red16(sqp[0]), r1 = red16(sqp[1]);
    float r2 = red16(sqp[2]), r3 = red16(sqp[3]);
    float r4 = red16(sqp[4]), r5 = red16(sqp[5]);
    float r6 = red16(sqp[6]), r7 = red16(sqp[7]);
    if (l < 8) {
        float s01 = (l & 1) ? r1 : r0;
        float s23 = (l & 1) ? r3 : r2;
        float s45 = (l & 1) ? r5 : r4;
        float s67 = (l & 1) ? r7 : r6;
        float a03 = (l & 2) ? s23 : s01;
        float a47 = (l & 2) ? s67 : s45;
        float sel = (l & 4) ? a47 : a03;
        float o = sel * sel * sigmoidf_fast(sel);    // Sq * silu(Sq)
        cell[crow + (size_t)l * 256] = f2bf(o);
    }
}

template<int DO_STAGE>
__device__ __forceinline__ void scan_chunk16(
    float (&K_)[CH][32], float (&Q_)[CH][32], float (&VB)[CH][8],
    float (&NK)[CH][32], float (&NQ)[CH][32], float (&NVB)[CH][8],
    const float*& gkn, const float*& gq, const float*& gv, const float*& gb,
    float (&k0A)[8], float (&k1A)[8], float (&q0A)[8], float (&q1A)[8],
    float (&vvA)[8], float (&bbA)[8],
    float (&k0B)[8], float (&k1B)[8], float (&q0B)[8], float (&q1B)[8],
    float (&vvB)[8], float (&bbB)[8],
    float& S0, float& S1, float (&sqp)[8],
    ushort* __restrict__ cell, size_t crow, int l, int iw, int j)
{
    float4 Lk0, Lk1, Lq0, Lq1;
    float Lv = 0.f, Lb = 0.f;
    if (DO_STAGE) {
        // issue-early: latency hides under the 16 steps below
        Lk0 = *reinterpret_cast<const float4*>(gkn);
        Lk1 = *reinterpret_cast<const float4*>(gkn + 8 * 256);
        Lq0 = *reinterpret_cast<const float4*>(gq);
        Lq1 = *reinterpret_cast<const float4*>(gq + 8 * 1024);
        Lv  = *gv;
        Lb  = *gb;
        gkn += CH * 256; gq += CH * 1024; gv += CH * 1024; gb += CH * 1024;
    }
    // batch-read rows 8-15 of CURRENT chunk into regB (used after steps 0-7)
    lds_load8(K_, Q_, VB, 8, l, iw, k0B, k1B, q0B, q1B, vvB, bbB);
    // steps 0-7 from regA (no memory ops on the serial path)
    steps8(k0A, k1A, q0A, q1A, vvA, bbA, S0, S1, sqp);
    flush8(sqp, cell, crow, l);
    if (DO_STAGE) {
        // write-late: globals had 8 steps to land
        *reinterpret_cast<float4*>(&NK[j >> 3][(j & 7) * 4]) = Lk0;
        *reinterpret_cast<float4*>(&NK[8 + (j >> 3)][(j & 7) * 4]) = Lk1;
        *reinterpret_cast<float4*>(&NQ[j >> 3][(j & 7) * 4]) = Lq0;
        *reinterpret_cast<float4*>(&NQ[8 + (j >> 3)][(j & 7) * 4]) = Lq1;
        NVB[j >> 2][j & 3] = Lv;
        NVB[j >> 2][4 + (j & 3)] = Lb;
        // batch-read next chunk's rows 0-7 into regA (used after steps 8-15)
        lds_load8(NK, NQ, NVB, 0, l, iw, k0A, k1A, q0A, q1A, vvA, bbA);
    }
    // steps 8-15 from regB
    steps8(k0B, k1B, q0B, q1B, vvB, bbB, S0, S1, sqp);
    flush8(sqp, cell, crow + (size_t)8 * 256, l);
}

__global__ __launch_bounds__(64, 1) void scan_kernel(
    const float* __restrict__ P,
    const float* __restrict__ KN,
    ushort* __restrict__ cell,     // [B*T, 256] bf16
    float* __restrict__ Sout)      // [B,H,32,32] fp32
{
    const int b    = blockIdx.x & 7;     // XCD-local batch slice
    const int r    = blockIdx.x >> 3;    // 0..63
    const int h    = r & 7;
    const int quad = r >> 3;             // 0..7
    const int j    = threadIdx.x;
    const int l    = j & 15;
    const int iw   = j >> 4;             // 0..3
    const int i    = quad * 4 + iw;

    __shared__ __align__(16) float sK0[CH][32], sK1[CH][32];
    __shared__ __align__(16) float sQ0[CH][32], sQ1[CH][32];
    __shared__ __align__(16) float sVB0[CH][8], sVB1[CH][8];

    const size_t bt0 = (size_t)b * TT;
    // per-lane coalesced source cursors (point at next chunk to stage)
    const float* gkn = KN + (bt0 + (j >> 3)) * 256 + h * 32 + (j & 7) * 4;
    const float* gq  = P  + (bt0 + (j >> 3)) * 1024 + 512 + h * 32 + (j & 7) * 4;
    const float* gv  = P  + (bt0 + (j >> 2)) * 1024 + 256 + h * 32 + quad * 4 + (j & 3);
    const float* gb  = P  + (bt0 + (j >> 2)) * 1024 + 768 + h * 32 + quad * 4 + (j & 3);

    float k0A[8], k1A[8], q0A[8], q1A[8], vvA[8], bbA[8];
    float k0B[8], k1B[8], q0B[8], q1B[8], vvB[8], bbB[8];
    float sqp[8];
    float S0 = 0.f, S1 = 0.f;
    const size_t cb = (size_t)b * TT * 256 + h * 32 + i;

    // prologue: stage chunk 0 into buf0, batch-read its rows 0-7 into regA
    {
        float4 K0v = *reinterpret_cast<const float4*>(gkn);
        float4 K1v = *reinterpret_cast<const float4*>(gkn + 8 * 256);
        float4 Q0v = *reinterpret_cast<const float4*>(gq);
        float4 Q1v = *reinterpret_cast<const float4*>(gq + 8 * 1024);
        float v0 = *gv, b0 = *gb;
        gkn += CH * 256; gq += CH * 1024; gv += CH * 1024; gb += CH * 1024;
        *reinterpret_cast<float4*>(&sK0[j >> 3][(j & 7) * 4]) = K0v;
        *reinterpret_cast<float4*>(&sK0[8 + (j >> 3)][(j & 7) * 4]) = K1v;
        *reinterpret_cast<float4*>(&sQ0[j >> 3][(j & 7) * 4]) = Q0v;
        *reinterpret_cast<float4*>(&sQ0[8 + (j >> 3)][(j & 7) * 4]) = Q1v;
        sVB0[j >> 2][j & 3] = v0;
        sVB0[j >> 2][4 + (j & 3)] = b0;
    }
    lds_load8(sK0, sQ0, sVB0, 0, l, iw, k0A, k1A, q0A, q1A, vvA, bbA);

    size_t crow = cb;
    for (int c = 0; c < 63; ++c) {
        scan_chunk16<1>(sK0, sQ0, sVB0, sK1, sQ1, sVB1,
                        gkn, gq, gv, gb,
                        k0A, k1A, q0A, q1A, vvA, bbA,
                        k0B, k1B, q0B, q1B, vvB, bbB,
                        S0, S1, sqp, cell, crow, l, iw, j);
        crow += (size_t)CH * 256;
        scan_chunk16<1>(sK1, sQ1, sVB1, sK0, sQ0, sVB0,
                        gkn, gq, gv, gb,
                        k0A, k1A, q0A, q1A, vvA, bbA,
                        k0B, k1B, q0B, q1B, vvB, bbB,
                        S0, S1, sqp, cell, crow, l, iw, j);
        crow += (size_t)CH * 256;
    }
    // chunk 126 (buf0), stages chunk 127 -> buf1 and preloads its rows 0-7
    scan_chunk16<1>(sK0, sQ0, sVB0, sK1, sQ1, sVB1,
                    gkn, gq, gv, gb,
                    k0A, k1A, q0A, q1A, vvA, bbA,
                    k0B, k1B, q0B, q1B, vvB, bbB,
                    S0, S1, sqp, cell, crow, l, iw, j);
    crow += (size_t)CH * 256;
    // chunk 127 (buf1), no staging
    scan_chunk16<0>(sK1, sQ1, sVB1, sK0, sQ0, sVB0,
                    gkn, gq, gv, gb,
                    k0A, k1A, q0A, q1A, vvA, bbA,
                    k0B, k1B, q0B, q1B, vvB, bbB,
                    S0, S1, sqp, cell, crow, l, iw, j);

    float* so = Sout + (((size_t)(b * HH + h)) * NNS + i) * NNS;
    so[l] = S0;
    so[l + 16] = S1;
}

extern "C" void kernel_launch(void* const* d_in, const int* in_sizes, int n_in,
                              void* d_out, int out_size, void* d_ws, size_t ws_size,
                              hipStream_t stream) {
    const float* x     = (const float*)d_in[0];
    const float* W_in  = (const float*)d_in[1];
    const float* W_k   = (const float*)d_in[2];
    const float* W_v   = (const float*)d_in[3];
    const float* W_q   = (const float*)d_in[4];
    const float* W_b   = (const float*)d_in[5];
    const float* b_b   = (const float*)d_in[6];
    const float* W_out = (const float*)d_in[7];
    float* out = (float*)d_out;

    const int M = MM;                                    // 16384
    float*  xp   = (float*)d_ws;                         // M*1024 fp32
    float*  P    = xp + (size_t)M * 1024;                // M*1024 fp32
    float*  KN   = P  + (size_t)M * 1024;                // M*256  fp32
    ushort* cell = (ushort*)(KN + (size_t)M * 256);      // M*256  bf16

    dim3 blk(256);
    dim3 g1(1024 / 64, M / 64);

    // 1) xp = silu(x @ W_in^T)
    gemm_split<1><<<g1, blk, 0, stream>>>(x, W_in, W_in + 256 * 1024,
                                          W_in + 512 * 1024, W_in + 768 * 1024,
                                          b_b, xp, M, 1024, 1024);
    // 2) P = xp @ [Wk;Wv;Wq;Wbeta]^T, beta block: sigmoid(. + b_beta)
    gemm_split<2><<<g1, blk, 0, stream>>>(xp, W_k, W_v, W_q, W_b,
                                          b_b, P, M, 1024, 1024);
    // 3) kn = k / (||k|| + 1e-6)  (parallel, memory-bound)
    kn_kernel<<<dim3((M * 256) / 256), blk, 0, stream>>>(P, KN);
    // 4) recurrent scan -> cell (bf16) + S_final (fp32, d_out tail)
    scan_kernel<<<dim3(512), dim3(64), 0, stream>>>(P, KN, cell, out + (size_t)M * 1024);
    // 5) y = cell @ W_out^T
    gemm_bf_a<<<g1, blk, 0, stream>>>(cell, W_out, W_out + 256 * 256,
                                      W_out + 512 * 256, W_out + 768 * 256,
                                      out, M, 1024, 256);
}

// Round 5
// 639.005 us; speedup vs baseline: 1.1759x; 1.0608x over previous
//
#include <hip/hip_runtime.h>
#include <hip/hip_bf16.h>

#define TT 2048
#define BB 8
#define HH 8
#define NNS 32
#define MM (BB * TT)
#define CH 16   // scan chunk rows staged in LDS

typedef __attribute__((ext_vector_type(8))) short short8;
typedef __attribute__((ext_vector_type(4))) float f32x4;

__device__ __forceinline__ float bf2f(ushort u) {
    return __uint_as_float(((unsigned)u) << 16);
}
__device__ __forceinline__ ushort f2bf(float f) {
    unsigned x = __float_as_uint(f);
    unsigned r = (x + 0x7fffu + ((x >> 16) & 1u)) >> 16;
    return (ushort)r;
}
__device__ __forceinline__ float sigmoidf_fast(float x) {
    float e = __builtin_amdgcn_exp2f(x * -1.4426950408889634f);
    return __builtin_amdgcn_rcpf(1.0f + e);
}
__device__ __forceinline__ float tanhf_fast(float x) {
    // 1 - 2/(e^{2x}+1); exp2 over/underflow saturates to +-1, no clamp needed
    float e = __builtin_amdgcn_exp2f(x * 2.8853900817779268f);
    return fmaf(-2.0f, __builtin_amdgcn_rcpf(e + 1.0f), 1.0f);
}

template<int CTRL>
__device__ __forceinline__ float dpp_add(float x) {
    int y = __builtin_amdgcn_update_dpp(0, __float_as_int(x), CTRL, 0xF, 0xF, true);
    return x + __int_as_float(y);
}
// 16-lane rotate-reduce: every lane of each 16-lane row ends with the row sum.
__device__ __forceinline__ float red16(float x) {
    x = dpp_add<0xB1>(x);    // quad_perm xor1
    x = dpp_add<0x4E>(x);    // quad_perm xor2
    x = dpp_add<0x124>(x);   // row_ror:4
    x = dpp_add<0x128>(x);   // row_ror:8
    return x;
}

// Split 8 fp32 -> bf16 hi + bf16 lo planes, stored as 16B each.
__device__ __forceinline__ void stage8_split(const float* __restrict__ src,
                                             ushort* __restrict__ hi,
                                             ushort* __restrict__ lo) {
    float4 x0 = *reinterpret_cast<const float4*>(src);
    float4 x1 = *reinterpret_cast<const float4*>(src + 4);
    float xs[8] = {x0.x, x0.y, x0.z, x0.w, x1.x, x1.y, x1.z, x1.w};
    ushort h[8], l[8];
#pragma unroll
    for (int i = 0; i < 8; ++i) {
        ushort hh = f2bf(xs[i]);
        h[i] = hh;
        l[i] = f2bf(xs[i] - bf2f(hh));
    }
    *reinterpret_cast<uint4*>(hi) = *reinterpret_cast<const uint4*>(h);
    *reinterpret_cast<uint4*>(lo) = *reinterpret_cast<const uint4*>(l);
}
__device__ __forceinline__ void stage8_hi(const float* __restrict__ src,
                                          ushort* __restrict__ hi) {
    float4 x0 = *reinterpret_cast<const float4*>(src);
    float4 x1 = *reinterpret_cast<const float4*>(src + 4);
    float xs[8] = {x0.x, x0.y, x0.z, x0.w, x1.x, x1.y, x1.z, x1.w};
    ushort h[8];
#pragma unroll
    for (int i = 0; i < 8; ++i) h[i] = f2bf(xs[i]);
    *reinterpret_cast<uint4*>(hi) = *reinterpret_cast<const uint4*>(h);
}

// ---------------- 128x128-tile split-bf16 GEMM ----------------
// C[M,N] = act(A[M,K] @ W[N,K]^T), fp32 in/out, split-bf16 MFMA (hi+lo, 3
// MFMAs per frag pair). 256 threads = 4 waves in 2x2; each wave owns a 64x64
// sub-tile as 4x4 16x16 frags. BK=32. Per K-step per wave: 48 MFMA vs 16
// ds_read_b128 (3x the MFMA:LDS ratio of the old 64x64 version), and staging
// bytes per output element are halved.
template<int ACT>
__global__ __launch_bounds__(256) void gemm_split(
    const float* __restrict__ A,
    const float* __restrict__ W0, const float* __restrict__ W1,
    const float* __restrict__ W2, const float* __restrict__ W3,
    const float* __restrict__ bbeta,
    float* __restrict__ C, int M, int N, int K)
{
    __shared__ __align__(16) ushort Ah[128][40], Al[128][40];
    __shared__ __align__(16) ushort Wh[128][40], Wl[128][40];
    const int n0 = blockIdx.x * 128;
    const int m0 = blockIdx.y * 128;
    const int t  = threadIdx.x;
    const int wave = t >> 6, lane = t & 63;
    const int lr = lane & 15, lq = lane >> 4;
    const int wm = wave >> 1, wn = wave & 1;

    const float* Wsel;
    {
        int wi = n0 >> 8;
        Wsel = (wi == 0) ? W0 : (wi == 1) ? W1 : (wi == 2) ? W2 : W3;
    }
    const int wr0 = n0 & 255;
    const int sr = t >> 1;          // staging row 0..127
    const int sc = (t & 1) * 16;    // staging col 0 or 16

    f32x4 acc[4][4];
#pragma unroll
    for (int mi = 0; mi < 4; ++mi)
#pragma unroll
        for (int ni = 0; ni < 4; ++ni) acc[mi][ni] = (f32x4){0.f, 0.f, 0.f, 0.f};

    for (int k0 = 0; k0 < K; k0 += 32) {
        __syncthreads();
        {
            const float* as = &A[(size_t)(m0 + sr) * K + k0 + sc];
            stage8_split(as,     &Ah[sr][sc],     &Al[sr][sc]);
            stage8_split(as + 8, &Ah[sr][sc + 8], &Al[sr][sc + 8]);
            const float* ws = &Wsel[(size_t)(wr0 + sr) * K + k0 + sc];
            stage8_split(ws,     &Wh[sr][sc],     &Wl[sr][sc]);
            stage8_split(ws + 8, &Wh[sr][sc + 8], &Wl[sr][sc + 8]);
        }
        __syncthreads();
        short8 ah[4], al[4], wh[4], wl[4];
#pragma unroll
        for (int mi = 0; mi < 4; ++mi) {
            ah[mi] = *reinterpret_cast<const short8*>(&Ah[wm * 64 + mi * 16 + lr][lq * 8]);
            al[mi] = *reinterpret_cast<const short8*>(&Al[wm * 64 + mi * 16 + lr][lq * 8]);
        }
#pragma unroll
        for (int ni = 0; ni < 4; ++ni) {
            wh[ni] = *reinterpret_cast<const short8*>(&Wh[wn * 64 + ni * 16 + lr][lq * 8]);
            wl[ni] = *reinterpret_cast<const short8*>(&Wl[wn * 64 + ni * 16 + lr][lq * 8]);
        }
#pragma unroll
        for (int mi = 0; mi < 4; ++mi) {
#pragma unroll
            for (int ni = 0; ni < 4; ++ni) {
                acc[mi][ni] = __builtin_amdgcn_mfma_f32_16x16x32_bf16(ah[mi], wh[ni], acc[mi][ni], 0, 0, 0);
                acc[mi][ni] = __builtin_amdgcn_mfma_f32_16x16x32_bf16(ah[mi], wl[ni], acc[mi][ni], 0, 0, 0);
                acc[mi][ni] = __builtin_amdgcn_mfma_f32_16x16x32_bf16(al[mi], wh[ni], acc[mi][ni], 0, 0, 0);
            }
        }
    }

#pragma unroll
    for (int mi = 0; mi < 4; ++mi) {
#pragma unroll
        for (int ni = 0; ni < 4; ++ni) {
#pragma unroll
            for (int r2 = 0; r2 < 4; ++r2) {
                int mg = m0 + wm * 64 + mi * 16 + lq * 4 + r2;
                int ng = n0 + wn * 64 + ni * 16 + lr;
                float v = acc[mi][ni][r2];
                if (ACT == 1) v = v * sigmoidf_fast(v);
                if (ACT == 2 && ng >= 768) v = sigmoidf_fast(v + bbeta[ng - 768]);
                C[(size_t)mg * N + ng] = v;
            }
        }
    }
}

// GEMM3: A is bf16 (cell), W fp32 -> bf16 hi only, C fp32. 128x128 tile.
__global__ __launch_bounds__(256) void gemm_bf_a(
    const ushort* __restrict__ A,
    const float* __restrict__ W0, const float* __restrict__ W1,
    const float* __restrict__ W2, const float* __restrict__ W3,
    float* __restrict__ C, int M, int N, int K)
{
    __shared__ __align__(16) ushort As[128][40];
    __shared__ __align__(16) ushort Ws[128][40];
    const int n0 = blockIdx.x * 128;
    const int m0 = blockIdx.y * 128;
    const int t  = threadIdx.x;
    const int wave = t >> 6, lane = t & 63;
    const int lr = lane & 15, lq = lane >> 4;
    const int wm = wave >> 1, wn = wave & 1;

    const float* Wsel;
    {
        int wi = n0 >> 8;
        Wsel = (wi == 0) ? W0 : (wi == 1) ? W1 : (wi == 2) ? W2 : W3;
    }
    const int wr0 = n0 & 255;
    const int sr = t >> 1;
    const int sc = (t & 1) * 16;

    f32x4 acc[4][4];
#pragma unroll
    for (int mi = 0; mi < 4; ++mi)
#pragma unroll
        for (int ni = 0; ni < 4; ++ni) acc[mi][ni] = (f32x4){0.f, 0.f, 0.f, 0.f};

    for (int k0 = 0; k0 < K; k0 += 32) {
        __syncthreads();
        {
            const ushort* as = &A[(size_t)(m0 + sr) * K + k0 + sc];
            *reinterpret_cast<uint4*>(&As[sr][sc])     = *reinterpret_cast<const uint4*>(as);
            *reinterpret_cast<uint4*>(&As[sr][sc + 8]) = *reinterpret_cast<const uint4*>(as + 8);
            const float* ws = &Wsel[(size_t)(wr0 + sr) * K + k0 + sc];
            stage8_hi(ws,     &Ws[sr][sc]);
            stage8_hi(ws + 8, &Ws[sr][sc + 8]);
        }
        __syncthreads();
        short8 af[4], wf[4];
#pragma unroll
        for (int mi = 0; mi < 4; ++mi)
            af[mi] = *reinterpret_cast<const short8*>(&As[wm * 64 + mi * 16 + lr][lq * 8]);
#pragma unroll
        for (int ni = 0; ni < 4; ++ni)
            wf[ni] = *reinterpret_cast<const short8*>(&Ws[wn * 64 + ni * 16 + lr][lq * 8]);
#pragma unroll
        for (int mi = 0; mi < 4; ++mi)
#pragma unroll
            for (int ni = 0; ni < 4; ++ni)
                acc[mi][ni] = __builtin_amdgcn_mfma_f32_16x16x32_bf16(af[mi], wf[ni], acc[mi][ni], 0, 0, 0);
    }

#pragma unroll
    for (int mi = 0; mi < 4; ++mi) {
#pragma unroll
        for (int ni = 0; ni < 4; ++ni) {
#pragma unroll
            for (int r2 = 0; r2 < 4; ++r2) {
                int mg = m0 + wm * 64 + mi * 16 + lq * 4 + r2;
                int ng = n0 + wn * 64 + ni * 16 + lr;
                C[(size_t)mg * N + ng] = acc[mi][ni][r2];
            }
        }
    }
}

// kn precompute: kn[b,t,h,j] = k / (||k||_h + 1e-6). Parallel over all (b,t,h).
__global__ __launch_bounds__(256) void kn_kernel(
    const float* __restrict__ P, float* __restrict__ KN)
{
    int idx = blockIdx.x * 256 + threadIdx.x;    // over MM*256
    int col = idx & 255;                          // h*32 + j
    int bt  = idx >> 8;
    float k = P[(size_t)bt * 1024 + col];
    float ks = k * k;
    ks += __shfl_xor(ks, 1, 32);  ks += __shfl_xor(ks, 2, 32);
    ks += __shfl_xor(ks, 4, 32);  ks += __shfl_xor(ks, 8, 32);
    ks += __shfl_xor(ks, 16, 32);
    KN[idx] = k * __builtin_amdgcn_rcpf(sqrtf(ks) + 1e-6f);
}

// ---------------- scan: LDS chunk-staged + 8-step register batching ----------
__device__ __forceinline__ void lds_load8(
    float (&K_)[CH][32], float (&Q_)[CH][32], float (&VB)[CH][8],
    int base, int l, int iw,
    float (&k0)[8], float (&k1)[8], float (&q0)[8], float (&q1)[8],
    float (&vv)[8], float (&bb)[8])
{
#pragma unroll
    for (int u = 0; u < 8; ++u) {
        k0[u] = K_[base + u][l];  k1[u] = K_[base + u][l + 16];
        q0[u] = Q_[base + u][l];  q1[u] = Q_[base + u][l + 16];
        vv[u] = VB[base + u][iw]; bb[u] = VB[base + u][iw + 4];
    }
}

__device__ __forceinline__ void steps8(
    float (&k0)[8], float (&k1)[8], float (&q0)[8], float (&q1)[8],
    float (&vv)[8], float (&bb)[8],
    float& S0, float& S1, float (&sqp)[8])
{
#pragma unroll
    for (int u = 0; u < 8; ++u) {
        // recurrence critical chain: fma + 4 DPP + sub + fma + tanh
        float p = red16(fmaf(S0, k0[u], S1 * k1[u]));
        float delta = vv[u] - p;
        S0 = tanhf_fast(fmaf(bb[u], S0, delta * k0[u]));
        S1 = tanhf_fast(fmaf(bb[u], S1, delta * k1[u]));
        // off-chain: 2-op partial only; reduce deferred to flush8
        sqp[u] = fmaf(S0, q0[u], S1 * q1[u]);
    }
}

__device__ __forceinline__ void flush8(
    float (&sqp)[8], ushort* __restrict__ cell, size_t crow, int l)
{
    // 8 independent reduces: pipeline, issue-bound not latency-bound
    float r0 = red16(sqp[0]), r1 = red16(sqp[1]);
    float r2 = red16(sqp[2]), r3 = red16(sqp[3]);
    float r4 = red16(sqp[4]), r5 = red16(sqp[5]);
    float r6 = red16(sqp[6]), r7 = red16(sqp[7]);
    if (l < 8) {
        float s01 = (l & 1) ? r1 : r0;
        float s23 = (l & 1) ? r3 : r2;
        float s45 = (l & 1) ? r5 : r4;
        float s67 = (l & 1) ? r7 : r6;
        float a03 = (l & 2) ? s23 : s01;
        float a47 = (l & 2) ? s67 : s45;
        float sel = (l & 4) ? a47 : a03;
        float o = sel * sel * sigmoidf_fast(sel);    // Sq * silu(Sq)
        cell[crow + (size_t)l * 256] = f2bf(o);
    }
}

template<int DO_STAGE>
__device__ __forceinline__ void scan_chunk16(
    float (&K_)[CH][32], float (&Q_)[CH][32], float (&VB)[CH][8],
    float (&NK)[CH][32], float (&NQ)[CH][32], float (&NVB)[CH][8],
    const float*& gkn, const float*& gq, const float*& gv, const float*& gb,
    float (&k0A)[8], float (&k1A)[8], float (&q0A)[8], float (&q1A)[8],
    float (&vvA)[8], float (&bbA)[8],
    float (&k0B)[8], float (&k1B)[8], float (&q0B)[8], float (&q1B)[8],
    float (&vvB)[8], float (&bbB)[8],
    float& S0, float& S1, float (&sqp)[8],
    ushort* __restrict__ cell, size_t crow, int l, int iw, int j)
{
    float4 Lk0, Lk1, Lq0, Lq1;
    float Lv = 0.f, Lb = 0.f;
    if (DO_STAGE) {
        // issue-early: latency hides under the 16 steps below
        Lk0 = *reinterpret_cast<const float4*>(gkn);
        Lk1 = *reinterpret_cast<const float4*>(gkn + 8 * 256);
        Lq0 = *reinterpret_cast<const float4*>(gq);
        Lq1 = *reinterpret_cast<const float4*>(gq + 8 * 1024);
        Lv  = *gv;
        Lb  = *gb;
        gkn += CH * 256; gq += CH * 1024; gv += CH * 1024; gb += CH * 1024;
    }
    // batch-read rows 8-15 of CURRENT chunk into regB (used after steps 0-7)
    lds_load8(K_, Q_, VB, 8, l, iw, k0B, k1B, q0B, q1B, vvB, bbB);
    // steps 0-7 from regA (no memory ops on the serial path)
    steps8(k0A, k1A, q0A, q1A, vvA, bbA, S0, S1, sqp);
    flush8(sqp, cell, crow, l);
    if (DO_STAGE) {
        // write-late: globals had 8 steps to land
        *reinterpret_cast<float4*>(&NK[j >> 3][(j & 7) * 4]) = Lk0;
        *reinterpret_cast<float4*>(&NK[8 + (j >> 3)][(j & 7) * 4]) = Lk1;
        *reinterpret_cast<float4*>(&NQ[j >> 3][(j & 7) * 4]) = Lq0;
        *reinterpret_cast<float4*>(&NQ[8 + (j >> 3)][(j & 7) * 4]) = Lq1;
        NVB[j >> 2][j & 3] = Lv;
        NVB[j >> 2][4 + (j & 3)] = Lb;
        // batch-read next chunk's rows 0-7 into regA (used after steps 8-15)
        lds_load8(NK, NQ, NVB, 0, l, iw, k0A, k1A, q0A, q1A, vvA, bbA);
    }
    // steps 8-15 from regB
    steps8(k0B, k1B, q0B, q1B, vvB, bbB, S0, S1, sqp);
    flush8(sqp, cell, crow + (size_t)8 * 256, l);
}

__global__ __launch_bounds__(64, 1) void scan_kernel(
    const float* __restrict__ P,
    const float* __restrict__ KN,
    ushort* __restrict__ cell,     // [B*T, 256] bf16
    float* __restrict__ Sout)      // [B,H,32,32] fp32
{
    const int b    = blockIdx.x & 7;     // XCD-local batch slice
    const int r    = blockIdx.x >> 3;    // 0..63
    const int h    = r & 7;
    const int quad = r >> 3;             // 0..7
    const int j    = threadIdx.x;
    const int l    = j & 15;
    const int iw   = j >> 4;             // 0..3
    const int i    = quad * 4 + iw;

    __shared__ __align__(16) float sK0[CH][32], sK1[CH][32];
    __shared__ __align__(16) float sQ0[CH][32], sQ1[CH][32];
    __shared__ __align__(16) float sVB0[CH][8], sVB1[CH][8];

    const size_t bt0 = (size_t)b * TT;
    // per-lane coalesced source cursors (point at next chunk to stage)
    const float* gkn = KN + (bt0 + (j >> 3)) * 256 + h * 32 + (j & 7) * 4;
    const float* gq  = P  + (bt0 + (j >> 3)) * 1024 + 512 + h * 32 + (j & 7) * 4;
    const float* gv  = P  + (bt0 + (j >> 2)) * 1024 + 256 + h * 32 + quad * 4 + (j & 3);
    const float* gb  = P  + (bt0 + (j >> 2)) * 1024 + 768 + h * 32 + quad * 4 + (j & 3);

    float k0A[8], k1A[8], q0A[8], q1A[8], vvA[8], bbA[8];
    float k0B[8], k1B[8], q0B[8], q1B[8], vvB[8], bbB[8];
    float sqp[8];
    float S0 = 0.f, S1 = 0.f;
    const size_t cb = (size_t)b * TT * 256 + h * 32 + i;

    // prologue: stage chunk 0 into buf0, batch-read its rows 0-7 into regA
    {
        float4 K0v = *reinterpret_cast<const float4*>(gkn);
        float4 K1v = *reinterpret_cast<const float4*>(gkn + 8 * 256);
        float4 Q0v = *reinterpret_cast<const float4*>(gq);
        float4 Q1v = *reinterpret_cast<const float4*>(gq + 8 * 1024);
        float v0 = *gv, b0 = *gb;
        gkn += CH * 256; gq += CH * 1024; gv += CH * 1024; gb += CH * 1024;
        *reinterpret_cast<float4*>(&sK0[j >> 3][(j & 7) * 4]) = K0v;
        *reinterpret_cast<float4*>(&sK0[8 + (j >> 3)][(j & 7) * 4]) = K1v;
        *reinterpret_cast<float4*>(&sQ0[j >> 3][(j & 7) * 4]) = Q0v;
        *reinterpret_cast<float4*>(&sQ0[8 + (j >> 3)][(j & 7) * 4]) = Q1v;
        sVB0[j >> 2][j & 3] = v0;
        sVB0[j >> 2][4 + (j & 3)] = b0;
    }
    lds_load8(sK0, sQ0, sVB0, 0, l, iw, k0A, k1A, q0A, q1A, vvA, bbA);

    size_t crow = cb;
    for (int c = 0; c < 63; ++c) {
        scan_chunk16<1>(sK0, sQ0, sVB0, sK1, sQ1, sVB1,
                        gkn, gq, gv, gb,
                        k0A, k1A, q0A, q1A, vvA, bbA,
                        k0B, k1B, q0B, q1B, vvB, bbB,
                        S0, S1, sqp, cell, crow, l, iw, j);
        crow += (size_t)CH * 256;
        scan_chunk16<1>(sK1, sQ1, sVB1, sK0, sQ0, sVB0,
                        gkn, gq, gv, gb,
                        k0A, k1A, q0A, q1A, vvA, bbA,
                        k0B, k1B, q0B, q1B, vvB, bbB,
                        S0, S1, sqp, cell, crow, l, iw, j);
        crow += (size_t)CH * 256;
    }
    // chunk 126 (buf0), stages chunk 127 -> buf1 and preloads its rows 0-7
    scan_chunk16<1>(sK0, sQ0, sVB0, sK1, sQ1, sVB1,
                    gkn, gq, gv, gb,
                    k0A, k1A, q0A, q1A, vvA, bbA,
                    k0B, k1B, q0B, q1B, vvB, bbB,
                    S0, S1, sqp, cell, crow, l, iw, j);
    crow += (size_t)CH * 256;
    // chunk 127 (buf1), no staging
    scan_chunk16<0>(sK1, sQ1, sVB1, sK0, sQ0, sVB0,
                    gkn, gq, gv, gb,
                    k0A, k1A, q0A, q1A, vvA, bbA,
                    k0B, k1B, q0B, q1B, vvB, bbB,
                    S0, S1, sqp, cell, crow, l, iw, j);

    float* so = Sout + (((size_t)(b * HH + h)) * NNS + i) * NNS;
    so[l] = S0;
    so[l + 16] = S1;
}

extern "C" void kernel_launch(void* const* d_in, const int* in_sizes, int n_in,
                              void* d_out, int out_size, void* d_ws, size_t ws_size,
                              hipStream_t stream) {
    const float* x     = (const float*)d_in[0];
    const float* W_in  = (const float*)d_in[1];
    const float* W_k   = (const float*)d_in[2];
    const float* W_v   = (const float*)d_in[3];
    const float* W_q   = (const float*)d_in[4];
    const float* W_b   = (const float*)d_in[5];
    const float* b_b   = (const float*)d_in[6];
    const float* W_out = (const float*)d_in[7];
    float* out = (float*)d_out;

    const int M = MM;                                    // 16384
    float*  xp   = (float*)d_ws;                         // M*1024 fp32
    float*  P    = xp + (size_t)M * 1024;                // M*1024 fp32
    float*  KN   = P  + (size_t)M * 1024;                // M*256  fp32
    ushort* cell = (ushort*)(KN + (size_t)M * 256);      // M*256  bf16

    dim3 blk(256);
    dim3 g1(1024 / 128, M / 128);

    // 1) xp = silu(x @ W_in^T)
    gemm_split<1><<<g1, blk, 0, stream>>>(x, W_in, W_in + 256 * 1024,
                                          W_in + 512 * 1024, W_in + 768 * 1024,
                                          b_b, xp, M, 1024, 1024);
    // 2) P = xp @ [Wk;Wv;Wq;Wbeta]^T, beta block: sigmoid(. + b_beta)
    gemm_split<2><<<g1, blk, 0, stream>>>(xp, W_k, W_v, W_q, W_b,
                                          b_b, P, M, 1024, 1024);
    // 3) kn = k / (||k|| + 1e-6)  (parallel, memory-bound)
    kn_kernel<<<dim3((M * 256) / 256), blk, 0, stream>>>(P, KN);
    // 4) recurrent scan -> cell (bf16) + S_final (fp32, d_out tail)
    scan_kernel<<<dim3(512), dim3(64), 0, stream>>>(P, KN, cell, out + (size_t)M * 1024);
    // 5) y = cell @ W_out^T
    gemm_bf_a<<<g1, blk, 0, stream>>>(cell, W_out, W_out + 256 * 256,
                                      W_out + 512 * 256, W_out + 768 * 256,
                                      out, M, 1024, 256);
}

// Round 6
// 593.720 us; speedup vs baseline: 1.2656x; 1.0763x over previous
//
#include <hip/hip_runtime.h>
#include <hip/hip_bf16.h>

#define TT 2048
#define BB 8
#define HH 8
#define NNS 32
#define MM (BB * TT)
#define CH 16   // scan chunk rows staged in LDS

typedef __attribute__((ext_vector_type(8))) short short8;
typedef __attribute__((ext_vector_type(4))) float f32x4;

__device__ __forceinline__ float bf2f(ushort u) {
    return __uint_as_float(((unsigned)u) << 16);
}
__device__ __forceinline__ ushort f2bf(float f) {
    unsigned x = __float_as_uint(f);
    unsigned r = (x + 0x7fffu + ((x >> 16) & 1u)) >> 16;
    return (ushort)r;
}
__device__ __forceinline__ float sigmoidf_fast(float x) {
    float e = __builtin_amdgcn_exp2f(x * -1.4426950408889634f);
    return __builtin_amdgcn_rcpf(1.0f + e);
}
__device__ __forceinline__ float tanhf_fast(float x) {
    // 1 - 2/(e^{2x}+1); exp2 over/underflow saturates to +-1, no clamp needed
    float e = __builtin_amdgcn_exp2f(x * 2.8853900817779268f);
    return fmaf(-2.0f, __builtin_amdgcn_rcpf(e + 1.0f), 1.0f);
}

template<int CTRL>
__device__ __forceinline__ float dpp_add(float x) {
    int y = __builtin_amdgcn_update_dpp(0, __float_as_int(x), CTRL, 0xF, 0xF, true);
    return x + __int_as_float(y);
}
// 16-lane rotate-reduce: every lane of each 16-lane row ends with the row sum.
__device__ __forceinline__ float red16(float x) {
    x = dpp_add<0xB1>(x);    // quad_perm xor1
    x = dpp_add<0x4E>(x);    // quad_perm xor2
    x = dpp_add<0x124>(x);   // row_ror:4
    x = dpp_add<0x128>(x);   // row_ror:8
    return x;
}

__device__ __forceinline__ void split8(const float4& x0, const float4& x1,
                                       ushort* __restrict__ h, ushort* __restrict__ l) {
    float xs[8] = {x0.x, x0.y, x0.z, x0.w, x1.x, x1.y, x1.z, x1.w};
#pragma unroll
    for (int i = 0; i < 8; ++i) {
        ushort hh = f2bf(xs[i]);
        h[i] = hh;
        l[i] = f2bf(xs[i] - bf2f(hh));
    }
}

// ---------------- conversion pre-passes (memory-bound) ----------------
// x fp32 -> hi/lo bf16 planes. 8 elems/thread, exact grid.
__global__ __launch_bounds__(256) void conv_x_kernel(
    const float* __restrict__ src, ushort* __restrict__ hi, ushort* __restrict__ lo)
{
    size_t e = ((size_t)blockIdx.x * 256 + threadIdx.x) * 8;
    float4 x0 = *reinterpret_cast<const float4*>(src + e);
    float4 x1 = *reinterpret_cast<const float4*>(src + e + 4);
    ushort h[8], l[8];
    split8(x0, x1, h, l);
    *reinterpret_cast<uint4*>(hi + e) = *reinterpret_cast<const uint4*>(h);
    *reinterpret_cast<uint4*>(lo + e) = *reinterpret_cast<const uint4*>(l);
}

// all weights -> planes in one launch. Regions: [0,1M) W_in -> W1h/W1l;
// [1M,2M) concat(Wk,Wv,Wq,Wb) -> W2h/W2l; [2M,2.25M) W_out -> W3h (hi only).
__global__ __launch_bounds__(256) void conv_w_kernel(
    const float* __restrict__ Wi, const float* __restrict__ Wk,
    const float* __restrict__ Wv, const float* __restrict__ Wq,
    const float* __restrict__ Wb, const float* __restrict__ Wo,
    ushort* __restrict__ W1h, ushort* __restrict__ W1l,
    ushort* __restrict__ W2h, ushort* __restrict__ W2l,
    ushort* __restrict__ W3h)
{
    size_t e = ((size_t)blockIdx.x * 256 + threadIdx.x) * 8;
    const float* s;
    ushort* dh; ushort* dl; size_t doff; bool dolo = true;
    if (e < 1048576) {
        s = Wi + e; dh = W1h; dl = W1l; doff = e;
    } else if (e < 2097152) {
        size_t u = e - 1048576;
        int wi = (int)(u >> 18);
        const float* sp = (wi == 0) ? Wk : (wi == 1) ? Wv : (wi == 2) ? Wq : Wb;
        s = sp + (u & 262143); dh = W2h; dl = W2l; doff = u;
    } else {
        size_t u = e - 2097152;
        s = Wo + u; dh = W3h; dl = nullptr; doff = u; dolo = false;
    }
    float4 x0 = *reinterpret_cast<const float4*>(s);
    float4 x1 = *reinterpret_cast<const float4*>(s + 4);
    ushort h[8], l[8];
    split8(x0, x1, h, l);
    *reinterpret_cast<uint4*>(dh + doff) = *reinterpret_cast<const uint4*>(h);
    if (dolo)
        *reinterpret_cast<uint4*>(dl + doff) = *reinterpret_cast<const uint4*>(l);
}

// ---------------- 128x128-tile pure-bf16-plane split GEMM ----------------
// C = act(A @ W^T) where A [M,K] and W [N,K] are given as bf16 hi/lo planes.
// No fp32->bf16 conversion in the hot loop: staging is pure uint4 copies.
// Double-buffered LDS + register prefetch: issue next K-step's 8 loads before
// the MFMA block, ds_write after it (T14 async split), 1 barrier per K-step.
// ACT==1: epilogue silu, output written as hi/lo bf16 planes (Ch/Cl).
// ACT==2: beta-block sigmoid epilogue, fp32 output (Cf).
template<int ACT>
__global__ __launch_bounds__(256, 2) void gemm_planes(
    const ushort* __restrict__ Ah_g, const ushort* __restrict__ Al_g,
    const ushort* __restrict__ Wh_g, const ushort* __restrict__ Wl_g,
    const float* __restrict__ bbeta,
    ushort* __restrict__ Ch, ushort* __restrict__ Cl,
    float* __restrict__ Cf, int M, int N, int K)
{
    __shared__ __align__(16) ushort sAh[2][128][40], sAl[2][128][40];
    __shared__ __align__(16) ushort sWh[2][128][40], sWl[2][128][40];
    const int n0 = blockIdx.x * 128;
    const int m0 = blockIdx.y * 128;
    const int t  = threadIdx.x;
    const int wave = t >> 6, lane = t & 63;
    const int lr = lane & 15, lq = lane >> 4;
    const int wm = wave >> 1, wn = wave & 1;

    const int sr = t >> 1;          // staging row 0..127
    const int sc = (t & 1) * 16;    // staging col 0 or 16

    const ushort* pAh = Ah_g + (size_t)(m0 + sr) * K + sc;
    const ushort* pAl = Al_g + (size_t)(m0 + sr) * K + sc;
    const ushort* pWh = Wh_g + (size_t)(n0 + sr) * K + sc;
    const ushort* pWl = Wl_g + (size_t)(n0 + sr) * K + sc;

    f32x4 acc[4][4];
#pragma unroll
    for (int mi = 0; mi < 4; ++mi)
#pragma unroll
        for (int ni = 0; ni < 4; ++ni) acc[mi][ni] = (f32x4){0.f, 0.f, 0.f, 0.f};

    const int NK = K >> 5;

    // prologue: stage K-step 0 into buf 0
    {
        uint4 a0 = *reinterpret_cast<const uint4*>(pAh);
        uint4 a1 = *reinterpret_cast<const uint4*>(pAh + 8);
        uint4 l0 = *reinterpret_cast<const uint4*>(pAl);
        uint4 l1 = *reinterpret_cast<const uint4*>(pAl + 8);
        uint4 w0 = *reinterpret_cast<const uint4*>(pWh);
        uint4 w1 = *reinterpret_cast<const uint4*>(pWh + 8);
        uint4 u0 = *reinterpret_cast<const uint4*>(pWl);
        uint4 u1 = *reinterpret_cast<const uint4*>(pWl + 8);
        *reinterpret_cast<uint4*>(&sAh[0][sr][sc])     = a0;
        *reinterpret_cast<uint4*>(&sAh[0][sr][sc + 8]) = a1;
        *reinterpret_cast<uint4*>(&sAl[0][sr][sc])     = l0;
        *reinterpret_cast<uint4*>(&sAl[0][sr][sc + 8]) = l1;
        *reinterpret_cast<uint4*>(&sWh[0][sr][sc])     = w0;
        *reinterpret_cast<uint4*>(&sWh[0][sr][sc + 8]) = w1;
        *reinterpret_cast<uint4*>(&sWl[0][sr][sc])     = u0;
        *reinterpret_cast<uint4*>(&sWl[0][sr][sc + 8]) = u1;
    }
    __syncthreads();

    for (int ks = 0; ks < NK; ++ks) {
        const int cur = ks & 1;
        uint4 a0, a1, l0, l1, w0, w1, u0, u1;
        const bool pf = (ks + 1 < NK);
        if (pf) {
            const int off = (ks + 1) << 5;
            a0 = *reinterpret_cast<const uint4*>(pAh + off);
            a1 = *reinterpret_cast<const uint4*>(pAh + off + 8);
            l0 = *reinterpret_cast<const uint4*>(pAl + off);
            l1 = *reinterpret_cast<const uint4*>(pAl + off + 8);
            w0 = *reinterpret_cast<const uint4*>(pWh + off);
            w1 = *reinterpret_cast<const uint4*>(pWh + off + 8);
            u0 = *reinterpret_cast<const uint4*>(pWl + off);
            u1 = *reinterpret_cast<const uint4*>(pWl + off + 8);
        }
        short8 ah[4], al[4], wh[4], wl[4];
#pragma unroll
        for (int mi = 0; mi < 4; ++mi) {
            ah[mi] = *reinterpret_cast<const short8*>(&sAh[cur][wm * 64 + mi * 16 + lr][lq * 8]);
            al[mi] = *reinterpret_cast<const short8*>(&sAl[cur][wm * 64 + mi * 16 + lr][lq * 8]);
        }
#pragma unroll
        for (int ni = 0; ni < 4; ++ni) {
            wh[ni] = *reinterpret_cast<const short8*>(&sWh[cur][wn * 64 + ni * 16 + lr][lq * 8]);
            wl[ni] = *reinterpret_cast<const short8*>(&sWl[cur][wn * 64 + ni * 16 + lr][lq * 8]);
        }
#pragma unroll
        for (int mi = 0; mi < 4; ++mi) {
#pragma unroll
            for (int ni = 0; ni < 4; ++ni) {
                acc[mi][ni] = __builtin_amdgcn_mfma_f32_16x16x32_bf16(ah[mi], wh[ni], acc[mi][ni], 0, 0, 0);
                acc[mi][ni] = __builtin_amdgcn_mfma_f32_16x16x32_bf16(ah[mi], wl[ni], acc[mi][ni], 0, 0, 0);
                acc[mi][ni] = __builtin_amdgcn_mfma_f32_16x16x32_bf16(al[mi], wh[ni], acc[mi][ni], 0, 0, 0);
            }
        }
        if (pf) {
            const int nxt = cur ^ 1;
            *reinterpret_cast<uint4*>(&sAh[nxt][sr][sc])     = a0;
            *reinterpret_cast<uint4*>(&sAh[nxt][sr][sc + 8]) = a1;
            *reinterpret_cast<uint4*>(&sAl[nxt][sr][sc])     = l0;
            *reinterpret_cast<uint4*>(&sAl[nxt][sr][sc + 8]) = l1;
            *reinterpret_cast<uint4*>(&sWh[nxt][sr][sc])     = w0;
            *reinterpret_cast<uint4*>(&sWh[nxt][sr][sc + 8]) = w1;
            *reinterpret_cast<uint4*>(&sWl[nxt][sr][sc])     = u0;
            *reinterpret_cast<uint4*>(&sWl[nxt][sr][sc + 8]) = u1;
        }
        __syncthreads();
    }

#pragma unroll
    for (int mi = 0; mi < 4; ++mi) {
#pragma unroll
        for (int ni = 0; ni < 4; ++ni) {
#pragma unroll
            for (int r2 = 0; r2 < 4; ++r2) {
                int mg = m0 + wm * 64 + mi * 16 + lq * 4 + r2;
                int ng = n0 + wn * 64 + ni * 16 + lr;
                float v = acc[mi][ni][r2];
                if (ACT == 1) {
                    v = v * sigmoidf_fast(v);
                    ushort h = f2bf(v);
                    ushort lo_ = f2bf(v - bf2f(h));
                    Ch[(size_t)mg * N + ng] = h;
                    Cl[(size_t)mg * N + ng] = lo_;
                } else {
                    if (ACT == 2 && ng >= 768) v = sigmoidf_fast(v + bbeta[ng - 768]);
                    Cf[(size_t)mg * N + ng] = v;
                }
            }
        }
    }
}

// GEMM3: A = cell bf16, W = pre-converted hi plane. Same pipeline, 1 MFMA/frag.
__global__ __launch_bounds__(256, 2) void gemm_cell(
    const ushort* __restrict__ A, const ushort* __restrict__ Wh_g,
    float* __restrict__ C, int M, int N, int K)
{
    __shared__ __align__(16) ushort sA[2][128][40];
    __shared__ __align__(16) ushort sW[2][128][40];
    const int n0 = blockIdx.x * 128;
    const int m0 = blockIdx.y * 128;
    const int t  = threadIdx.x;
    const int wave = t >> 6, lane = t & 63;
    const int lr = lane & 15, lq = lane >> 4;
    const int wm = wave >> 1, wn = wave & 1;
    const int sr = t >> 1;
    const int sc = (t & 1) * 16;

    const ushort* pA = A    + (size_t)(m0 + sr) * K + sc;
    const ushort* pW = Wh_g + (size_t)(n0 + sr) * K + sc;

    f32x4 acc[4][4];
#pragma unroll
    for (int mi = 0; mi < 4; ++mi)
#pragma unroll
        for (int ni = 0; ni < 4; ++ni) acc[mi][ni] = (f32x4){0.f, 0.f, 0.f, 0.f};

    const int NK = K >> 5;
    {
        uint4 a0 = *reinterpret_cast<const uint4*>(pA);
        uint4 a1 = *reinterpret_cast<const uint4*>(pA + 8);
        uint4 w0 = *reinterpret_cast<const uint4*>(pW);
        uint4 w1 = *reinterpret_cast<const uint4*>(pW + 8);
        *reinterpret_cast<uint4*>(&sA[0][sr][sc])     = a0;
        *reinterpret_cast<uint4*>(&sA[0][sr][sc + 8]) = a1;
        *reinterpret_cast<uint4*>(&sW[0][sr][sc])     = w0;
        *reinterpret_cast<uint4*>(&sW[0][sr][sc + 8]) = w1;
    }
    __syncthreads();

    for (int ks = 0; ks < NK; ++ks) {
        const int cur = ks & 1;
        uint4 a0, a1, w0, w1;
        const bool pf = (ks + 1 < NK);
        if (pf) {
            const int off = (ks + 1) << 5;
            a0 = *reinterpret_cast<const uint4*>(pA + off);
            a1 = *reinterpret_cast<const uint4*>(pA + off + 8);
            w0 = *reinterpret_cast<const uint4*>(pW + off);
            w1 = *reinterpret_cast<const uint4*>(pW + off + 8);
        }
        short8 af[4], wf[4];
#pragma unroll
        for (int mi = 0; mi < 4; ++mi)
            af[mi] = *reinterpret_cast<const short8*>(&sA[cur][wm * 64 + mi * 16 + lr][lq * 8]);
#pragma unroll
        for (int ni = 0; ni < 4; ++ni)
            wf[ni] = *reinterpret_cast<const short8*>(&sW[cur][wn * 64 + ni * 16 + lr][lq * 8]);
#pragma unroll
        for (int mi = 0; mi < 4; ++mi)
#pragma unroll
            for (int ni = 0; ni < 4; ++ni)
                acc[mi][ni] = __builtin_amdgcn_mfma_f32_16x16x32_bf16(af[mi], wf[ni], acc[mi][ni], 0, 0, 0);
        if (pf) {
            const int nxt = cur ^ 1;
            *reinterpret_cast<uint4*>(&sA[nxt][sr][sc])     = a0;
            *reinterpret_cast<uint4*>(&sA[nxt][sr][sc + 8]) = a1;
            *reinterpret_cast<uint4*>(&sW[nxt][sr][sc])     = w0;
            *reinterpret_cast<uint4*>(&sW[nxt][sr][sc + 8]) = w1;
        }
        __syncthreads();
    }

#pragma unroll
    for (int mi = 0; mi < 4; ++mi) {
#pragma unroll
        for (int ni = 0; ni < 4; ++ni) {
#pragma unroll
            for (int r2 = 0; r2 < 4; ++r2) {
                int mg = m0 + wm * 64 + mi * 16 + lq * 4 + r2;
                int ng = n0 + wn * 64 + ni * 16 + lr;
                C[(size_t)mg * N + ng] = acc[mi][ni][r2];
            }
        }
    }
}

// kn precompute: kn[b,t,h,j] = k / (||k||_h + 1e-6). Parallel over all (b,t,h).
__global__ __launch_bounds__(256) void kn_kernel(
    const float* __restrict__ P, float* __restrict__ KN)
{
    int idx = blockIdx.x * 256 + threadIdx.x;    // over MM*256
    int col = idx & 255;                          // h*32 + j
    int bt  = idx >> 8;
    float k = P[(size_t)bt * 1024 + col];
    float ks = k * k;
    ks += __shfl_xor(ks, 1, 32);  ks += __shfl_xor(ks, 2, 32);
    ks += __shfl_xor(ks, 4, 32);  ks += __shfl_xor(ks, 8, 32);
    ks += __shfl_xor(ks, 16, 32);
    KN[idx] = k * __builtin_amdgcn_rcpf(sqrtf(ks) + 1e-6f);
}

// ---------------- scan: LDS chunk-staged + 8-step register batching ----------
__device__ __forceinline__ void lds_load8(
    float (&K_)[CH][32], float (&Q_)[CH][32], float (&VB)[CH][8],
    int base, int l, int iw,
    float (&k0)[8], float (&k1)[8], float (&q0)[8], float (&q1)[8],
    float (&vv)[8], float (&bb)[8])
{
#pragma unroll
    for (int u = 0; u < 8; ++u) {
        k0[u] = K_[base + u][l];  k1[u] = K_[base + u][l + 16];
        q0[u] = Q_[base + u][l];  q1[u] = Q_[base + u][l + 16];
        vv[u] = VB[base + u][iw]; bb[u] = VB[base + u][iw + 4];
    }
}

__device__ __forceinline__ void steps8(
    float (&k0)[8], float (&k1)[8], float (&q0)[8], float (&q1)[8],
    float (&vv)[8], float (&bb)[8],
    float& S0, float& S1, float (&sqp)[8])
{
#pragma unroll
    for (int u = 0; u < 8; ++u) {
        // recurrence critical chain: fma + 4 DPP + sub + fma + tanh
        float p = red16(fmaf(S0, k0[u], S1 * k1[u]));
        float delta = vv[u] - p;
        S0 = tanhf_fast(fmaf(bb[u], S0, delta * k0[u]));
        S1 = tanhf_fast(fmaf(bb[u], S1, delta * k1[u]));
        // off-chain: 2-op partial only; reduce deferred to flush8
        sqp[u] = fmaf(S0, q0[u], S1 * q1[u]);
    }
}

__device__ __forceinline__ void flush8(
    float (&sqp)[8], ushort* __restrict__ cell, size_t crow, int l)
{
    // 8 independent reduces: pipeline, issue-bound not latency-bound
    float r0 = red16(sqp[0]), r1 = red16(sqp[1]);
    float r2 = red16(sqp[2]), r3 = red16(sqp[3]);
    float r4 = red16(sqp[4]), r5 = red16(sqp[5]);
    float r6 = red16(sqp[6]), r7 = red16(sqp[7]);
    if (l < 8) {
        float s01 = (l & 1) ? r1 : r0;
        float s23 = (l & 1) ? r3 : r2;
        float s45 = (l & 1) ? r5 : r4;
        float s67 = (l & 1) ? r7 : r6;
        float a03 = (l & 2) ? s23 : s01;
        float a47 = (l & 2) ? s67 : s45;
        float sel = (l & 4) ? a47 : a03;
        float o = sel * sel * sigmoidf_fast(sel);    // Sq * silu(Sq)
        cell[crow + (size_t)l * 256] = f2bf(o);
    }
}

template<int DO_STAGE>
__device__ __forceinline__ void scan_chunk16(
    float (&K_)[CH][32], float (&Q_)[CH][32], float (&VB)[CH][8],
    float (&NK)[CH][32], float (&NQ)[CH][32], float (&NVB)[CH][8],
    const float*& gkn, const float*& gq, const float*& gv, const float*& gb,
    float (&k0A)[8], float (&k1A)[8], float (&q0A)[8], float (&q1A)[8],
    float (&vvA)[8], float (&bbA)[8],
    float (&k0B)[8], float (&k1B)[8], float (&q0B)[8], float (&q1B)[8],
    float (&vvB)[8], float (&bbB)[8],
    float& S0, float& S1, float (&sqp)[8],
    ushort* __restrict__ cell, size_t crow, int l, int iw, int j)
{
    float4 Lk0, Lk1, Lq0, Lq1;
    float Lv = 0.f, Lb = 0.f;
    if (DO_STAGE) {
        // issue-early: latency hides under the 16 steps below
        Lk0 = *reinterpret_cast<const float4*>(gkn);
        Lk1 = *reinterpret_cast<const float4*>(gkn + 8 * 256);
        Lq0 = *reinterpret_cast<const float4*>(gq);
        Lq1 = *reinterpret_cast<const float4*>(gq + 8 * 1024);
        Lv  = *gv;
        Lb  = *gb;
        gkn += CH * 256; gq += CH * 1024; gv += CH * 1024; gb += CH * 1024;
    }
    // batch-read rows 8-15 of CURRENT chunk into regB (used after steps 0-7)
    lds_load8(K_, Q_, VB, 8, l, iw, k0B, k1B, q0B, q1B, vvB, bbB);
    // steps 0-7 from regA (no memory ops on the serial path)
    steps8(k0A, k1A, q0A, q1A, vvA, bbA, S0, S1, sqp);
    flush8(sqp, cell, crow, l);
    if (DO_STAGE) {
        // write-late: globals had 8 steps to land
        *reinterpret_cast<float4*>(&NK[j >> 3][(j & 7) * 4]) = Lk0;
        *reinterpret_cast<float4*>(&NK[8 + (j >> 3)][(j & 7) * 4]) = Lk1;
        *reinterpret_cast<float4*>(&NQ[j >> 3][(j & 7) * 4]) = Lq0;
        *reinterpret_cast<float4*>(&NQ[8 + (j >> 3)][(j & 7) * 4]) = Lq1;
        NVB[j >> 2][j & 3] = Lv;
        NVB[j >> 2][4 + (j & 3)] = Lb;
        // batch-read next chunk's rows 0-7 into regA (used after steps 8-15)
        lds_load8(NK, NQ, NVB, 0, l, iw, k0A, k1A, q0A, q1A, vvA, bbA);
    }
    // steps 8-15 from regB
    steps8(k0B, k1B, q0B, q1B, vvB, bbB, S0, S1, sqp);
    flush8(sqp, cell, crow + (size_t)8 * 256, l);
}

__global__ __launch_bounds__(64, 1) void scan_kernel(
    const float* __restrict__ P,
    const float* __restrict__ KN,
    ushort* __restrict__ cell,     // [B*T, 256] bf16
    float* __restrict__ Sout)      // [B,H,32,32] fp32
{
    const int b    = blockIdx.x & 7;     // XCD-local batch slice
    const int r    = blockIdx.x >> 3;    // 0..63
    const int h    = r & 7;
    const int quad = r >> 3;             // 0..7
    const int j    = threadIdx.x;
    const int l    = j & 15;
    const int iw   = j >> 4;             // 0..3
    const int i    = quad * 4 + iw;

    __shared__ __align__(16) float sK0[CH][32], sK1[CH][32];
    __shared__ __align__(16) float sQ0[CH][32], sQ1[CH][32];
    __shared__ __align__(16) float sVB0[CH][8], sVB1[CH][8];

    const size_t bt0 = (size_t)b * TT;
    // per-lane coalesced source cursors (point at next chunk to stage)
    const float* gkn = KN + (bt0 + (j >> 3)) * 256 + h * 32 + (j & 7) * 4;
    const float* gq  = P  + (bt0 + (j >> 3)) * 1024 + 512 + h * 32 + (j & 7) * 4;
    const float* gv  = P  + (bt0 + (j >> 2)) * 1024 + 256 + h * 32 + quad * 4 + (j & 3);
    const float* gb  = P  + (bt0 + (j >> 2)) * 1024 + 768 + h * 32 + quad * 4 + (j & 3);

    float k0A[8], k1A[8], q0A[8], q1A[8], vvA[8], bbA[8];
    float k0B[8], k1B[8], q0B[8], q1B[8], vvB[8], bbB[8];
    float sqp[8];
    float S0 = 0.f, S1 = 0.f;
    const size_t cb = (size_t)b * TT * 256 + h * 32 + i;

    // prologue: stage chunk 0 into buf0, batch-read its rows 0-7 into regA
    {
        float4 K0v = *reinterpret_cast<const float4*>(gkn);
        float4 K1v = *reinterpret_cast<const float4*>(gkn + 8 * 256);
        float4 Q0v = *reinterpret_cast<const float4*>(gq);
        float4 Q1v = *reinterpret_cast<const float4*>(gq + 8 * 1024);
        float v0 = *gv, b0 = *gb;
        gkn += CH * 256; gq += CH * 1024; gv += CH * 1024; gb += CH * 1024;
        *reinterpret_cast<float4*>(&sK0[j >> 3][(j & 7) * 4]) = K0v;
        *reinterpret_cast<float4*>(&sK0[8 + (j >> 3)][(j & 7) * 4]) = K1v;
        *reinterpret_cast<float4*>(&sQ0[j >> 3][(j & 7) * 4]) = Q0v;
        *reinterpret_cast<float4*>(&sQ0[8 + (j >> 3)][(j & 7) * 4]) = Q1v;
        sVB0[j >> 2][j & 3] = v0;
        sVB0[j >> 2][4 + (j & 3)] = b0;
    }
    lds_load8(sK0, sQ0, sVB0, 0, l, iw, k0A, k1A, q0A, q1A, vvA, bbA);

    size_t crow = cb;
    for (int c = 0; c < 63; ++c) {
        scan_chunk16<1>(sK0, sQ0, sVB0, sK1, sQ1, sVB1,
                        gkn, gq, gv, gb,
                        k0A, k1A, q0A, q1A, vvA, bbA,
                        k0B, k1B, q0B, q1B, vvB, bbB,
                        S0, S1, sqp, cell, crow, l, iw, j);
        crow += (size_t)CH * 256;
        scan_chunk16<1>(sK1, sQ1, sVB1, sK0, sQ0, sVB0,
                        gkn, gq, gv, gb,
                        k0A, k1A, q0A, q1A, vvA, bbA,
                        k0B, k1B, q0B, q1B, vvB, bbB,
                        S0, S1, sqp, cell, crow, l, iw, j);
        crow += (size_t)CH * 256;
    }
    // chunk 126 (buf0), stages chunk 127 -> buf1 and preloads its rows 0-7
    scan_chunk16<1>(sK0, sQ0, sVB0, sK1, sQ1, sVB1,
                    gkn, gq, gv, gb,
                    k0A, k1A, q0A, q1A, vvA, bbA,
                    k0B, k1B, q0B, q1B, vvB, bbB,
                    S0, S1, sqp, cell, crow, l, iw, j);
    crow += (size_t)CH * 256;
    // chunk 127 (buf1), no staging
    scan_chunk16<0>(sK1, sQ1, sVB1, sK0, sQ0, sVB0,
                    gkn, gq, gv, gb,
                    k0A, k1A, q0A, q1A, vvA, bbA,
                    k0B, k1B, q0B, q1B, vvB, bbB,
                    S0, S1, sqp, cell, crow, l, iw, j);

    float* so = Sout + (((size_t)(b * HH + h)) * NNS + i) * NNS;
    so[l] = S0;
    so[l + 16] = S1;
}

extern "C" void kernel_launch(void* const* d_in, const int* in_sizes, int n_in,
                              void* d_out, int out_size, void* d_ws, size_t ws_size,
                              hipStream_t stream) {
    const float* x     = (const float*)d_in[0];
    const float* W_in  = (const float*)d_in[1];
    const float* W_k   = (const float*)d_in[2];
    const float* W_v   = (const float*)d_in[3];
    const float* W_q   = (const float*)d_in[4];
    const float* W_b   = (const float*)d_in[5];
    const float* b_b   = (const float*)d_in[6];
    const float* W_out = (const float*)d_in[7];
    float* out = (float*)d_out;

    const int M = MM;                                    // 16384
    float* f = (float*)d_ws;
    // region A: P fp32 [M,1024] — ALIASES Xh/Xl (dead before gemm2 writes P)
    float*  P    = f;
    ushort* Xh   = (ushort*)f;
    ushort* Xl   = Xh + (size_t)M * 1024;
    // region B: xp hi/lo planes [M,1024] each
    ushort* xpH  = (ushort*)(f + (size_t)M * 1024);
    ushort* xpL  = xpH + (size_t)M * 1024;
    // region C/D
    float*  KN   = f + (size_t)2 * M * 1024;             // M*256 fp32
    ushort* cell = (ushort*)(KN + (size_t)M * 256);      // M*256 bf16
    ushort* wb   = cell + (size_t)M * 256;               // weight planes
    ushort* W1h = wb;                    // 1M
    ushort* W1l = W1h + 1048576;         // 1M
    ushort* W2h = W1l + 1048576;         // 1M
    ushort* W2l = W2h + 1048576;         // 1M
    ushort* W3h = W2l + 1048576;         // 256K

    dim3 blk(256);
    dim3 g1(1024 / 128, M / 128);

    // 0) conversions (memory-bound pre-passes)
    conv_x_kernel<<<dim3((M * 1024) / (8 * 256)), blk, 0, stream>>>(x, Xh, Xl);
    conv_w_kernel<<<dim3(2359296 / (8 * 256)), blk, 0, stream>>>(
        W_in, W_k, W_v, W_q, W_b, W_out, W1h, W1l, W2h, W2l, W3h);
    // 1) xp = silu(x @ W_in^T), written directly as hi/lo planes
    gemm_planes<1><<<g1, blk, 0, stream>>>(Xh, Xl, W1h, W1l, b_b,
                                           xpH, xpL, nullptr, M, 1024, 1024);
    // 2) P = xp @ [Wk;Wv;Wq;Wbeta]^T, beta block: sigmoid(. + b_beta)
    gemm_planes<2><<<g1, blk, 0, stream>>>(xpH, xpL, W2h, W2l, b_b,
                                           nullptr, nullptr, P, M, 1024, 1024);
    // 3) kn = k / (||k|| + 1e-6)
    kn_kernel<<<dim3((M * 256) / 256), blk, 0, stream>>>(P, KN);
    // 4) recurrent scan -> cell (bf16) + S_final (fp32, d_out tail)
    scan_kernel<<<dim3(512), dim3(64), 0, stream>>>(P, KN, cell, out + (size_t)M * 1024);
    // 5) y = cell @ W_out^T
    gemm_cell<<<g1, blk, 0, stream>>>(cell, W3h, out, M, 1024, 256);
}

// Round 7
// 569.137 us; speedup vs baseline: 1.3202x; 1.0432x over previous
//
#include <hip/hip_runtime.h>
#include <hip/hip_bf16.h>

#define TT 2048
#define BB 8
#define HH 8
#define NNS 32
#define MM (BB * TT)
#define CH 16   // scan chunk rows staged in LDS

typedef __attribute__((ext_vector_type(8))) short short8;
typedef __attribute__((ext_vector_type(4))) float f32x4;

__device__ __forceinline__ float bf2f(ushort u) {
    return __uint_as_float(((unsigned)u) << 16);
}
__device__ __forceinline__ ushort f2bf(float f) {
    unsigned x = __float_as_uint(f);
    unsigned r = (x + 0x7fffu + ((x >> 16) & 1u)) >> 16;
    return (ushort)r;
}
__device__ __forceinline__ float sigmoidf_fast(float x) {
    float e = __builtin_amdgcn_exp2f(x * -1.4426950408889634f);
    return __builtin_amdgcn_rcpf(1.0f + e);
}
__device__ __forceinline__ float tanhf_fast(float x) {
    // 1 - 2/(e^{2x}+1); exp2 over/underflow saturates to +-1, no clamp needed
    float e = __builtin_amdgcn_exp2f(x * 2.8853900817779268f);
    return fmaf(-2.0f, __builtin_amdgcn_rcpf(e + 1.0f), 1.0f);
}

// async global->LDS, 16B per lane. Dest must be wave-uniform base + lane*16.
__device__ __forceinline__ void gl16(const void* g, void* l) {
    auto gp = (const __attribute__((address_space(1))) unsigned int*)g;
    auto lp = (__attribute__((address_space(3))) unsigned int*)l;
    __builtin_amdgcn_global_load_lds(gp, lp, 16, 0, 0);
}

template<int CTRL>
__device__ __forceinline__ float dpp_add(float x) {
    int y = __builtin_amdgcn_update_dpp(0, __float_as_int(x), CTRL, 0xF, 0xF, true);
    return x + __int_as_float(y);
}
// 16-lane rotate-reduce: every lane of each 16-lane row ends with the row sum.
__device__ __forceinline__ float red16(float x) {
    x = dpp_add<0xB1>(x);    // quad_perm xor1
    x = dpp_add<0x4E>(x);    // quad_perm xor2
    x = dpp_add<0x124>(x);   // row_ror:4
    x = dpp_add<0x128>(x);   // row_ror:8
    return x;
}

__device__ __forceinline__ void split8(const float4& x0, const float4& x1,
                                       ushort* __restrict__ h, ushort* __restrict__ l) {
    float xs[8] = {x0.x, x0.y, x0.z, x0.w, x1.x, x1.y, x1.z, x1.w};
#pragma unroll
    for (int i = 0; i < 8; ++i) {
        ushort hh = f2bf(xs[i]);
        h[i] = hh;
        l[i] = f2bf(xs[i] - bf2f(hh));
    }
}

// ---------------- conversion pre-passes (memory-bound) ----------------
__global__ __launch_bounds__(256) void conv_x_kernel(
    const float* __restrict__ src, ushort* __restrict__ hi, ushort* __restrict__ lo)
{
    size_t e = ((size_t)blockIdx.x * 256 + threadIdx.x) * 8;
    float4 x0 = *reinterpret_cast<const float4*>(src + e);
    float4 x1 = *reinterpret_cast<const float4*>(src + e + 4);
    ushort h[8], l[8];
    split8(x0, x1, h, l);
    *reinterpret_cast<uint4*>(hi + e) = *reinterpret_cast<const uint4*>(h);
    *reinterpret_cast<uint4*>(lo + e) = *reinterpret_cast<const uint4*>(l);
}

// all weights -> planes. [0,1M) W_in -> W1h/W1l; [1M,2M) concat(Wk,Wv,Wq,Wb)
// -> W2h/W2l; [2M,2.25M) W_out -> W3h (hi only).
__global__ __launch_bounds__(256) void conv_w_kernel(
    const float* __restrict__ Wi, const float* __restrict__ Wk,
    const float* __restrict__ Wv, const float* __restrict__ Wq,
    const float* __restrict__ Wb, const float* __restrict__ Wo,
    ushort* __restrict__ W1h, ushort* __restrict__ W1l,
    ushort* __restrict__ W2h, ushort* __restrict__ W2l,
    ushort* __restrict__ W3h)
{
    size_t e = ((size_t)blockIdx.x * 256 + threadIdx.x) * 8;
    const float* s;
    ushort* dh; ushort* dl; size_t doff; bool dolo = true;
    if (e < 1048576) {
        s = Wi + e; dh = W1h; dl = W1l; doff = e;
    } else if (e < 2097152) {
        size_t u = e - 1048576;
        int wi = (int)(u >> 18);
        const float* sp = (wi == 0) ? Wk : (wi == 1) ? Wv : (wi == 2) ? Wq : Wb;
        s = sp + (u & 262143); dh = W2h; dl = W2l; doff = u;
    } else {
        size_t u = e - 2097152;
        s = Wo + u; dh = W3h; dl = nullptr; doff = u; dolo = false;
    }
    float4 x0 = *reinterpret_cast<const float4*>(s);
    float4 x1 = *reinterpret_cast<const float4*>(s + 4);
    ushort h[8], l[8];
    split8(x0, x1, h, l);
    *reinterpret_cast<uint4*>(dh + doff) = *reinterpret_cast<const uint4*>(h);
    if (dolo)
        *reinterpret_cast<uint4*>(dl + doff) = *reinterpret_cast<const uint4*>(l);
}

// ---------------- 128x128-tile split GEMM, global_load_lds staging ----------
// m97 structure: unpadded [128][32] LDS, width-16 global_load_lds (8/thread/
// K-step for 4 plane arrays), 2 barriers per K-step (compiler drains vmcnt at
// the 2nd), 32KB LDS -> 3 blocks/CU for inter-block overlap of the drain.
// XCD-chunk block swizzle: 8 n-blocks sharing an A-tile land on one XCD's L2.
template<int ACT>
__global__ __launch_bounds__(256, 3) void gemm_planes(
    const ushort* __restrict__ Ah_g, const ushort* __restrict__ Al_g,
    const ushort* __restrict__ Wh_g, const ushort* __restrict__ Wl_g,
    const float* __restrict__ bbeta,
    ushort* __restrict__ Ch, ushort* __restrict__ Cl,
    float* __restrict__ Cf, int M, int N, int K)
{
    __shared__ __align__(16) ushort sAh[128][32], sAl[128][32];
    __shared__ __align__(16) ushort sWh[128][32], sWl[128][32];
    const int t = threadIdx.x;
    const int wave = t >> 6, lane = t & 63;
    const int lr = lane & 15, lq = lane >> 4;
    const int wm = wave >> 1, wn = wave & 1;

    // XCD-aware bijective swizzle (nwg=1024, 1024%8==0)
    const int bid = blockIdx.y * 8 + blockIdx.x;
    const int swz = (bid & 7) * 128 + (bid >> 3);
    const int n0 = (swz & 7) * 128;
    const int m0 = (swz >> 3) * 128;

    // staging map: (wave, pp, lane) -> LDS byte wave*2048 + pp*1024 + lane*16
    //            -> row = wave*32 + pp*16 + lane/4, col-elems = (lane&3)*8
    const int rs0 = wave * 32 + (lane >> 2);
    const int rs1 = rs0 + 16;
    const int ce  = (lane & 3) * 8;
    const ushort* gA0h = Ah_g + (size_t)(m0 + rs0) * K + ce;
    const ushort* gA1h = Ah_g + (size_t)(m0 + rs1) * K + ce;
    const ushort* gA0l = Al_g + (size_t)(m0 + rs0) * K + ce;
    const ushort* gA1l = Al_g + (size_t)(m0 + rs1) * K + ce;
    const ushort* gW0h = Wh_g + (size_t)(n0 + rs0) * K + ce;
    const ushort* gW1h = Wh_g + (size_t)(n0 + rs1) * K + ce;
    const ushort* gW0l = Wl_g + (size_t)(n0 + rs0) * K + ce;
    const ushort* gW1l = Wl_g + (size_t)(n0 + rs1) * K + ce;
    const int lb = wave * 2048 + lane * 16;
    char* LAh = (char*)&sAh[0][0];
    char* LAl = (char*)&sAl[0][0];
    char* LWh = (char*)&sWh[0][0];
    char* LWl = (char*)&sWl[0][0];

    f32x4 acc[4][4];
#pragma unroll
    for (int mi = 0; mi < 4; ++mi)
#pragma unroll
        for (int ni = 0; ni < 4; ++ni) acc[mi][ni] = (f32x4){0.f, 0.f, 0.f, 0.f};

    const int NK = K >> 5;
    for (int ks = 0; ks < NK; ++ks) {
        const int k0 = ks << 5;
        __syncthreads();   // prior reads of LDS done -> safe to overwrite
        gl16(gA0h + k0, LAh + lb);  gl16(gA1h + k0, LAh + lb + 1024);
        gl16(gA0l + k0, LAl + lb);  gl16(gA1l + k0, LAl + lb + 1024);
        gl16(gW0h + k0, LWh + lb);  gl16(gW1h + k0, LWh + lb + 1024);
        gl16(gW0l + k0, LWl + lb);  gl16(gW1l + k0, LWl + lb + 1024);
        __syncthreads();   // compiler drains vmcnt(0): staged data visible
        short8 ah[4], al[4], wh[4], wl[4];
#pragma unroll
        for (int mi = 0; mi < 4; ++mi) {
            ah[mi] = *reinterpret_cast<const short8*>(&sAh[wm * 64 + mi * 16 + lr][lq * 8]);
            al[mi] = *reinterpret_cast<const short8*>(&sAl[wm * 64 + mi * 16 + lr][lq * 8]);
        }
#pragma unroll
        for (int ni = 0; ni < 4; ++ni) {
            wh[ni] = *reinterpret_cast<const short8*>(&sWh[wn * 64 + ni * 16 + lr][lq * 8]);
            wl[ni] = *reinterpret_cast<const short8*>(&sWl[wn * 64 + ni * 16 + lr][lq * 8]);
        }
#pragma unroll
        for (int mi = 0; mi < 4; ++mi) {
#pragma unroll
            for (int ni = 0; ni < 4; ++ni) {
                acc[mi][ni] = __builtin_amdgcn_mfma_f32_16x16x32_bf16(ah[mi], wh[ni], acc[mi][ni], 0, 0, 0);
                acc[mi][ni] = __builtin_amdgcn_mfma_f32_16x16x32_bf16(ah[mi], wl[ni], acc[mi][ni], 0, 0, 0);
                acc[mi][ni] = __builtin_amdgcn_mfma_f32_16x16x32_bf16(al[mi], wh[ni], acc[mi][ni], 0, 0, 0);
            }
        }
    }

#pragma unroll
    for (int mi = 0; mi < 4; ++mi) {
#pragma unroll
        for (int ni = 0; ni < 4; ++ni) {
#pragma unroll
            for (int r2 = 0; r2 < 4; ++r2) {
                int mg = m0 + wm * 64 + mi * 16 + lq * 4 + r2;
                int ng = n0 + wn * 64 + ni * 16 + lr;
                float v = acc[mi][ni][r2];
                if (ACT == 1) {
                    v = v * sigmoidf_fast(v);
                    ushort h = f2bf(v);
                    ushort lo_ = f2bf(v - bf2f(h));
                    Ch[(size_t)mg * N + ng] = h;
                    Cl[(size_t)mg * N + ng] = lo_;
                } else {
                    if (ACT == 2 && ng >= 768) v = sigmoidf_fast(v + bbeta[ng - 768]);
                    Cf[(size_t)mg * N + ng] = v;
                }
            }
        }
    }
}

// GEMM3: A = cell bf16, W = pre-converted hi plane. Same gload_lds structure.
__global__ __launch_bounds__(256, 4) void gemm_cell(
    const ushort* __restrict__ A, const ushort* __restrict__ Wh_g,
    float* __restrict__ C, int M, int N, int K)
{
    __shared__ __align__(16) ushort sA[128][32];
    __shared__ __align__(16) ushort sW[128][32];
    const int t = threadIdx.x;
    const int wave = t >> 6, lane = t & 63;
    const int lr = lane & 15, lq = lane >> 4;
    const int wm = wave >> 1, wn = wave & 1;

    const int bid = blockIdx.y * 8 + blockIdx.x;
    const int swz = (bid & 7) * 128 + (bid >> 3);
    const int n0 = (swz & 7) * 128;
    const int m0 = (swz >> 3) * 128;

    const int rs0 = wave * 32 + (lane >> 2);
    const int rs1 = rs0 + 16;
    const int ce  = (lane & 3) * 8;
    const ushort* gA0 = A    + (size_t)(m0 + rs0) * K + ce;
    const ushort* gA1 = A    + (size_t)(m0 + rs1) * K + ce;
    const ushort* gW0 = Wh_g + (size_t)(n0 + rs0) * K + ce;
    const ushort* gW1 = Wh_g + (size_t)(n0 + rs1) * K + ce;
    const int lb = wave * 2048 + lane * 16;
    char* LA = (char*)&sA[0][0];
    char* LW = (char*)&sW[0][0];

    f32x4 acc[4][4];
#pragma unroll
    for (int mi = 0; mi < 4; ++mi)
#pragma unroll
        for (int ni = 0; ni < 4; ++ni) acc[mi][ni] = (f32x4){0.f, 0.f, 0.f, 0.f};

    const int NK = K >> 5;
    for (int ks = 0; ks < NK; ++ks) {
        const int k0 = ks << 5;
        __syncthreads();
        gl16(gA0 + k0, LA + lb);  gl16(gA1 + k0, LA + lb + 1024);
        gl16(gW0 + k0, LW + lb);  gl16(gW1 + k0, LW + lb + 1024);
        __syncthreads();
        short8 af[4], wf[4];
#pragma unroll
        for (int mi = 0; mi < 4; ++mi)
            af[mi] = *reinterpret_cast<const short8*>(&sA[wm * 64 + mi * 16 + lr][lq * 8]);
#pragma unroll
        for (int ni = 0; ni < 4; ++ni)
            wf[ni] = *reinterpret_cast<const short8*>(&sW[wn * 64 + ni * 16 + lr][lq * 8]);
#pragma unroll
        for (int mi = 0; mi < 4; ++mi)
#pragma unroll
            for (int ni = 0; ni < 4; ++ni)
                acc[mi][ni] = __builtin_amdgcn_mfma_f32_16x16x32_bf16(af[mi], wf[ni], acc[mi][ni], 0, 0, 0);
    }

#pragma unroll
    for (int mi = 0; mi < 4; ++mi) {
#pragma unroll
        for (int ni = 0; ni < 4; ++ni) {
#pragma unroll
            for (int r2 = 0; r2 < 4; ++r2) {
                int mg = m0 + wm * 64 + mi * 16 + lq * 4 + r2;
                int ng = n0 + wn * 64 + ni * 16 + lr;
                C[(size_t)mg * N + ng] = acc[mi][ni][r2];
            }
        }
    }
}

// kn precompute: kn[b,t,h,j] = k / (||k||_h + 1e-6). Parallel over all (b,t,h).
__global__ __launch_bounds__(256) void kn_kernel(
    const float* __restrict__ P, float* __restrict__ KN)
{
    int idx = blockIdx.x * 256 + threadIdx.x;    // over MM*256
    int col = idx & 255;                          // h*32 + j
    int bt  = idx >> 8;
    float k = P[(size_t)bt * 1024 + col];
    float ks = k * k;
    ks += __shfl_xor(ks, 1, 32);  ks += __shfl_xor(ks, 2, 32);
    ks += __shfl_xor(ks, 4, 32);  ks += __shfl_xor(ks, 8, 32);
    ks += __shfl_xor(ks, 16, 32);
    KN[idx] = k * __builtin_amdgcn_rcpf(sqrtf(ks) + 1e-6f);
}

// ---------------- scan: LDS chunk-staged + 8-step register batching ----------
__device__ __forceinline__ void lds_load8(
    float (&K_)[CH][32], float (&Q_)[CH][32], float (&VB)[CH][8],
    int base, int l, int iw,
    float (&k0)[8], float (&k1)[8], float (&q0)[8], float (&q1)[8],
    float (&vv)[8], float (&bb)[8])
{
#pragma unroll
    for (int u = 0; u < 8; ++u) {
        k0[u] = K_[base + u][l];  k1[u] = K_[base + u][l + 16];
        q0[u] = Q_[base + u][l];  q1[u] = Q_[base + u][l + 16];
        vv[u] = VB[base + u][iw]; bb[u] = VB[base + u][iw + 4];
    }
}

__device__ __forceinline__ void steps8(
    float (&k0)[8], float (&k1)[8], float (&q0)[8], float (&q1)[8],
    float (&vv)[8], float (&bb)[8],
    float& S0, float& S1, float (&sqp)[8])
{
#pragma unroll
    for (int u = 0; u < 8; ++u) {
        // recurrence critical chain: fma + 4 DPP + sub + fma + tanh
        float p = red16(fmaf(S0, k0[u], S1 * k1[u]));
        float delta = vv[u] - p;
        S0 = tanhf_fast(fmaf(bb[u], S0, delta * k0[u]));
        S1 = tanhf_fast(fmaf(bb[u], S1, delta * k1[u]));
        // off-chain: 2-op partial only; reduce deferred to flush8
        sqp[u] = fmaf(S0, q0[u], S1 * q1[u]);
    }
}

__device__ __forceinline__ void flush8(
    float (&sqp)[8], ushort* __restrict__ cell, size_t crow, int l)
{
    // 8 independent reduces: pipeline, issue-bound not latency-bound
    float r0 = red16(sqp[0]), r1 = red16(sqp[1]);
    float r2 = red16(sqp[2]), r3 = red16(sqp[3]);
    float r4 = red16(sqp[4]), r5 = red16(sqp[5]);
    float r6 = red16(sqp[6]), r7 = red16(sqp[7]);
    if (l < 8) {
        float s01 = (l & 1) ? r1 : r0;
        float s23 = (l & 1) ? r3 : r2;
        float s45 = (l & 1) ? r5 : r4;
        float s67 = (l & 1) ? r7 : r6;
        float a03 = (l & 2) ? s23 : s01;
        float a47 = (l & 2) ? s67 : s45;
        float sel = (l & 4) ? a47 : a03;
        float o = sel * sel * sigmoidf_fast(sel);    // Sq * silu(Sq)
        cell[crow + (size_t)l * 256] = f2bf(o);
    }
}

template<int DO_STAGE>
__device__ __forceinline__ void scan_chunk16(
    float (&K_)[CH][32], float (&Q_)[CH][32], float (&VB)[CH][8],
    float (&NK)[CH][32], float (&NQ)[CH][32], float (&NVB)[CH][8],
    const float*& gkn, const float*& gq, const float*& gv, const float*& gb,
    float (&k0A)[8], float (&k1A)[8], float (&q0A)[8], float (&q1A)[8],
    float (&vvA)[8], float (&bbA)[8],
    float (&k0B)[8], float (&k1B)[8], float (&q0B)[8], float (&q1B)[8],
    float (&vvB)[8], float (&bbB)[8],
    float& S0, float& S1, float (&sqp)[8],
    ushort* __restrict__ cell, size_t crow, int l, int iw, int j)
{
    float4 Lk0, Lk1, Lq0, Lq1;
    float Lv = 0.f, Lb = 0.f;
    if (DO_STAGE) {
        // issue-early: latency hides under the 16 steps below
        Lk0 = *reinterpret_cast<const float4*>(gkn);
        Lk1 = *reinterpret_cast<const float4*>(gkn + 8 * 256);
        Lq0 = *reinterpret_cast<const float4*>(gq);
        Lq1 = *reinterpret_cast<const float4*>(gq + 8 * 1024);
        Lv  = *gv;
        Lb  = *gb;
        gkn += CH * 256; gq += CH * 1024; gv += CH * 1024; gb += CH * 1024;
    }
    // batch-read rows 8-15 of CURRENT chunk into regB (used after steps 0-7)
    lds_load8(K_, Q_, VB, 8, l, iw, k0B, k1B, q0B, q1B, vvB, bbB);
    // steps 0-7 from regA (no memory ops on the serial path)
    steps8(k0A, k1A, q0A, q1A, vvA, bbA, S0, S1, sqp);
    flush8(sqp, cell, crow, l);
    if (DO_STAGE) {
        // write-late: globals had 8 steps to land
        *reinterpret_cast<float4*>(&NK[j >> 3][(j & 7) * 4]) = Lk0;
        *reinterpret_cast<float4*>(&NK[8 + (j >> 3)][(j & 7) * 4]) = Lk1;
        *reinterpret_cast<float4*>(&NQ[j >> 3][(j & 7) * 4]) = Lq0;
        *reinterpret_cast<float4*>(&NQ[8 + (j >> 3)][(j & 7) * 4]) = Lq1;
        NVB[j >> 2][j & 3] = Lv;
        NVB[j >> 2][4 + (j & 3)] = Lb;
        // batch-read next chunk's rows 0-7 into regA (used after steps 8-15)
        lds_load8(NK, NQ, NVB, 0, l, iw, k0A, k1A, q0A, q1A, vvA, bbA);
    }
    // steps 8-15 from regB
    steps8(k0B, k1B, q0B, q1B, vvB, bbB, S0, S1, sqp);
    flush8(sqp, cell, crow + (size_t)8 * 256, l);
}

__global__ __launch_bounds__(64, 1) void scan_kernel(
    const float* __restrict__ P,
    const float* __restrict__ KN,
    ushort* __restrict__ cell,     // [B*T, 256] bf16
    float* __restrict__ Sout)      // [B,H,32,32] fp32
{
    const int b    = blockIdx.x & 7;     // XCD-local batch slice
    const int r    = blockIdx.x >> 3;    // 0..63
    const int h    = r & 7;
    const int quad = r >> 3;             // 0..7
    const int j    = threadIdx.x;
    const int l    = j & 15;
    const int iw   = j >> 4;             // 0..3
    const int i    = quad * 4 + iw;

    __shared__ __align__(16) float sK0[CH][32], sK1[CH][32];
    __shared__ __align__(16) float sQ0[CH][32], sQ1[CH][32];
    __shared__ __align__(16) float sVB0[CH][8], sVB1[CH][8];

    const size_t bt0 = (size_t)b * TT;
    // per-lane coalesced source cursors (point at next chunk to stage)
    const float* gkn = KN + (bt0 + (j >> 3)) * 256 + h * 32 + (j & 7) * 4;
    const float* gq  = P  + (bt0 + (j >> 3)) * 1024 + 512 + h * 32 + (j & 7) * 4;
    const float* gv  = P  + (bt0 + (j >> 2)) * 1024 + 256 + h * 32 + quad * 4 + (j & 3);
    const float* gb  = P  + (bt0 + (j >> 2)) * 1024 + 768 + h * 32 + quad * 4 + (j & 3);

    float k0A[8], k1A[8], q0A[8], q1A[8], vvA[8], bbA[8];
    float k0B[8], k1B[8], q0B[8], q1B[8], vvB[8], bbB[8];
    float sqp[8];
    float S0 = 0.f, S1 = 0.f;
    const size_t cb = (size_t)b * TT * 256 + h * 32 + i;

    // prologue: stage chunk 0 into buf0, batch-read its rows 0-7 into regA
    {
        float4 K0v = *reinterpret_cast<const float4*>(gkn);
        float4 K1v = *reinterpret_cast<const float4*>(gkn + 8 * 256);
        float4 Q0v = *reinterpret_cast<const float4*>(gq);
        float4 Q1v = *reinterpret_cast<const float4*>(gq + 8 * 1024);
        float v0 = *gv, b0 = *gb;
        gkn += CH * 256; gq += CH * 1024; gv += CH * 1024; gb += CH * 1024;
        *reinterpret_cast<float4*>(&sK0[j >> 3][(j & 7) * 4]) = K0v;
        *reinterpret_cast<float4*>(&sK0[8 + (j >> 3)][(j & 7) * 4]) = K1v;
        *reinterpret_cast<float4*>(&sQ0[j >> 3][(j & 7) * 4]) = Q0v;
        *reinterpret_cast<float4*>(&sQ0[8 + (j >> 3)][(j & 7) * 4]) = Q1v;
        sVB0[j >> 2][j & 3] = v0;
        sVB0[j >> 2][4 + (j & 3)] = b0;
    }
    lds_load8(sK0, sQ0, sVB0, 0, l, iw, k0A, k1A, q0A, q1A, vvA, bbA);

    size_t crow = cb;
    for (int c = 0; c < 63; ++c) {
        scan_chunk16<1>(sK0, sQ0, sVB0, sK1, sQ1, sVB1,
                        gkn, gq, gv, gb,
                        k0A, k1A, q0A, q1A, vvA, bbA,
                        k0B, k1B, q0B, q1B, vvB, bbB,
                        S0, S1, sqp, cell, crow, l, iw, j);
        crow += (size_t)CH * 256;
        scan_chunk16<1>(sK1, sQ1, sVB1, sK0, sQ0, sVB0,
                        gkn, gq, gv, gb,
                        k0A, k1A, q0A, q1A, vvA, bbA,
                        k0B, k1B, q0B, q1B, vvB, bbB,
                        S0, S1, sqp, cell, crow, l, iw, j);
        crow += (size_t)CH * 256;
    }
    // chunk 126 (buf0), stages chunk 127 -> buf1 and preloads its rows 0-7
    scan_chunk16<1>(sK0, sQ0, sVB0, sK1, sQ1, sVB1,
                    gkn, gq, gv, gb,
                    k0A, k1A, q0A, q1A, vvA, bbA,
                    k0B, k1B, q0B, q1B, vvB, bbB,
                    S0, S1, sqp, cell, crow, l, iw, j);
    crow += (size_t)CH * 256;
    // chunk 127 (buf1), no staging
    scan_chunk16<0>(sK1, sQ1, sVB1, sK0, sQ0, sVB0,
                    gkn, gq, gv, gb,
                    k0A, k1A, q0A, q1A, vvA, bbA,
                    k0B, k1B, q0B, q1B, vvB, bbB,
                    S0, S1, sqp, cell, crow, l, iw, j);

    float* so = Sout + (((size_t)(b * HH + h)) * NNS + i) * NNS;
    so[l] = S0;
    so[l + 16] = S1;
}

extern "C" void kernel_launch(void* const* d_in, const int* in_sizes, int n_in,
                              void* d_out, int out_size, void* d_ws, size_t ws_size,
                              hipStream_t stream) {
    const float* x     = (const float*)d_in[0];
    const float* W_in  = (const float*)d_in[1];
    const float* W_k   = (const float*)d_in[2];
    const float* W_v   = (const float*)d_in[3];
    const float* W_q   = (const float*)d_in[4];
    const float* W_b   = (const float*)d_in[5];
    const float* b_b   = (const float*)d_in[6];
    const float* W_out = (const float*)d_in[7];
    float* out = (float*)d_out;

    const int M = MM;                                    // 16384
    float* f = (float*)d_ws;
    // region A: P fp32 [M,1024] — ALIASES Xh/Xl (dead before gemm2 writes P)
    float*  P    = f;
    ushort* Xh   = (ushort*)f;
    ushort* Xl   = Xh + (size_t)M * 1024;
    // region B: xp hi/lo planes [M,1024] each
    ushort* xpH  = (ushort*)(f + (size_t)M * 1024);
    ushort* xpL  = xpH + (size_t)M * 1024;
    // region C/D
    float*  KN   = f + (size_t)2 * M * 1024;             // M*256 fp32
    ushort* cell = (ushort*)(KN + (size_t)M * 256);      // M*256 bf16
    ushort* wb   = cell + (size_t)M * 256;               // weight planes
    ushort* W1h = wb;                    // 1M
    ushort* W1l = W1h + 1048576;         // 1M
    ushort* W2h = W1l + 1048576;         // 1M
    ushort* W2l = W2h + 1048576;         // 1M
    ushort* W3h = W2l + 1048576;         // 256K

    dim3 blk(256);
    dim3 g1(1024 / 128, M / 128);

    // 0) conversions (memory-bound pre-passes)
    conv_x_kernel<<<dim3((M * 1024) / (8 * 256)), blk, 0, stream>>>(x, Xh, Xl);
    conv_w_kernel<<<dim3(2359296 / (8 * 256)), blk, 0, stream>>>(
        W_in, W_k, W_v, W_q, W_b, W_out, W1h, W1l, W2h, W2l, W3h);
    // 1) xp = silu(x @ W_in^T), written directly as hi/lo planes
    gemm_planes<1><<<g1, blk, 0, stream>>>(Xh, Xl, W1h, W1l, b_b,
                                           xpH, xpL, nullptr, M, 1024, 1024);
    // 2) P = xp @ [Wk;Wv;Wq;Wbeta]^T, beta block: sigmoid(. + b_beta)
    gemm_planes<2><<<g1, blk, 0, stream>>>(xpH, xpL, W2h, W2l, b_b,
                                           nullptr, nullptr, P, M, 1024, 1024);
    // 3) kn = k / (||k|| + 1e-6)
    kn_kernel<<<dim3((M * 256) / 256), blk, 0, stream>>>(P, KN);
    // 4) recurrent scan -> cell (bf16) + S_final (fp32, d_out tail)
    scan_kernel<<<dim3(512), dim3(64), 0, stream>>>(P, KN, cell, out + (size_t)M * 1024);
    // 5) y = cell @ W_out^T
    gemm_cell<<<g1, blk, 0, stream>>>(cell, W3h, out, M, 1024, 256);
}